// Round 2
// baseline (1936.825 us; speedup 1.0000x reference)
//
#include <hip/hip_runtime.h>
#include <math.h>

#define N_NODES_C 50000
#define N_EDGES_C 1600000
#define N_GRAPHS_C 2048

static __device__ __forceinline__ int lowerBound(const int* __restrict__ a, int n, int v) {
    int lo = 0, hi = n;
    while (lo < hi) {
        int mid = (lo + hi) >> 1;
        if (a[mid] < v) lo = mid + 1; else hi = mid;
    }
    return lo;
}

// ---------------- CSR build ----------------

__global__ void init_deg_kernel(int* __restrict__ deg, int n) {
    int i = blockIdx.x * blockDim.x + threadIdx.x;
    if (i < n) deg[i] = 1;  // self-loop contributes 1
}

__global__ void count_kernel(const int* __restrict__ ei, int* __restrict__ deg, int E) {
    for (int e = blockIdx.x * blockDim.x + threadIdx.x; e < E; e += gridDim.x * blockDim.x)
        atomicAdd(&deg[ei[E + e]], 1);  // dst row of edge_index
}

__global__ __launch_bounds__(1024) void scan_kernel(int* __restrict__ deg_cursor,
                                                    int* __restrict__ rowptr, int n) {
    __shared__ int part[1024];
    int t = threadIdx.x;
    int chunk = (n + 1023) >> 10;
    int beg = t * chunk;
    int end = min(beg + chunk, n);
    int s = 0;
    for (int i = beg; i < end; i++) s += deg_cursor[i];
    part[t] = s;
    __syncthreads();
    for (int off = 1; off < 1024; off <<= 1) {
        int v = (t >= off) ? part[t - off] : 0;
        __syncthreads();
        part[t] += v;
        __syncthreads();
    }
    if (t == 0) rowptr[n] = part[1023];
    int run = (t == 0) ? 0 : part[t - 1];
    for (int i = beg; i < end; i++) {
        int d = deg_cursor[i];
        rowptr[i] = run;
        deg_cursor[i] = run;  // becomes scatter cursor (in-place)
        run += d;
    }
}

__global__ void scatter_kernel(const int* __restrict__ ei, int* __restrict__ cursor,
                               int* __restrict__ csr, int E, int n) {
    int total = E + n;
    for (int idx = blockIdx.x * blockDim.x + threadIdx.x; idx < total; idx += gridDim.x * blockDim.x) {
        int s_, d_;
        if (idx < E) { s_ = ei[idx]; d_ = ei[E + idx]; }
        else         { s_ = d_ = idx - E; }  // self loop
        int pos = atomicAdd(&cursor[d_], 1);
        csr[pos] = s_;
    }
}

// ---------------- per-layer: h = x@W, als = h.a_src, ald = h.a_dst ----------------

template<int DIN, int DOUT>
__global__ __launch_bounds__(DOUT) void linear_att_kernel(
    const float* __restrict__ x, const float* __restrict__ W,
    const float* __restrict__ avs, const float* __restrict__ avd,
    float* __restrict__ h, float* __restrict__ als, float* __restrict__ ald, int n) {
    __shared__ float Wl[DIN * DOUT];
    __shared__ float xs[DIN];
    __shared__ float red[(DOUT / 64) * 2];
    int t = threadIdx.x;
    for (int i = t; i < DIN * DOUT; i += DOUT) Wl[i] = W[i];
    float a_s = avs[t], a_d = avd[t];
    __syncthreads();
    for (int node = blockIdx.x; node < n; node += gridDim.x) {
        for (int i = t; i < DIN; i += DOUT) xs[i] = x[node * DIN + i];  // FIX: strided (DIN may exceed blockDim)
        __syncthreads();
        float acc = 0.f;
#pragma unroll
        for (int k = 0; k < DIN; k++) acc += xs[k] * Wl[k * DOUT + t];
        h[node * DOUT + t] = acc;
        float ps = acc * a_s, pd = acc * a_d;
#pragma unroll
        for (int o = 32; o > 0; o >>= 1) { ps += __shfl_down(ps, o); pd += __shfl_down(pd, o); }
        int wv = t >> 6, ln = t & 63;
        if (ln == 0) { red[wv * 2] = ps; red[wv * 2 + 1] = pd; }
        __syncthreads();
        if (t == 0) {
            float S = red[0], D = red[1];
#pragma unroll
            for (int w = 1; w < DOUT / 64; w++) { S += red[w * 2]; D += red[w * 2 + 1]; }
            als[node] = S; ald[node] = D;
        }
        __syncthreads();
    }
}

// ---------------- per-layer: softmax-weighted aggregation, one wave per dst node ----------------

template<int DOUT>
__global__ __launch_bounds__(256) void gat_agg_kernel(
    const int* __restrict__ rowptr, const int* __restrict__ csr,
    const float* __restrict__ als, const float* __restrict__ ald,
    const float* __restrict__ h, const float* __restrict__ bias,
    float* __restrict__ xout, int n) {
    int node = blockIdx.x * 4 + (threadIdx.x >> 6);
    if (node >= n) return;
    int lane = threadIdx.x & 63;
    int beg = rowptr[node], end = rowptr[node + 1];
    float adi = ald[node];

    // pass A: online softmax stats, lane-parallel over incoming edges
    float m = -INFINITY, s = 0.f;
    int src0 = 0; float e0 = -INFINITY;
    bool first = true;
    for (int idx = beg + lane; idx < end; idx += 64) {
        int src = csr[idx];
        float e = als[src] + adi;
        e = (e > 0.f) ? e : 0.2f * e;  // leaky_relu 0.2
        if (first) { src0 = src; e0 = e; first = false; }
        if (e > m) { s *= expf(m - e); m = e; }
        s += expf(e - m);
    }
#pragma unroll
    for (int o = 1; o < 64; o <<= 1) {
        float m2 = __shfl_xor(m, o);
        float s2 = __shfl_xor(s, o);
        float M = fmaxf(m, m2);
        float t1 = (m == M) ? s : s * expf(m - M);
        float t2 = (m2 == M) ? s2 : s2 * expf(m2 - M);
        m = M; s = t1 + t2;
    }
    float inv_den = 1.f / s;

    // pass B: column-parallel weighted sum of h[src]
    constexpr int CPL = DOUT / 64;
    float acc[CPL];
#pragma unroll
    for (int c = 0; c < CPL; c++) acc[c] = 0.f;
    int deg = end - beg;
    int lim = deg < 64 ? deg : 64;
    for (int j = 0; j < lim; j++) {
        int src = __shfl(src0, j);
        float e = __shfl(e0, j);
        float alpha = expf(e - m) * inv_den;
        const float* hr = h + (size_t)src * DOUT;
#pragma unroll
        for (int c = 0; c < CPL; c++) acc[c] += alpha * hr[c * 64 + lane];
    }
    for (int idx = beg + 64; idx < end; idx++) {  // rare: degree > 64
        int src = csr[idx];
        float e = als[src] + adi;
        e = (e > 0.f) ? e : 0.2f * e;
        float alpha = expf(e - m) * inv_den;
        const float* hr = h + (size_t)src * DOUT;
#pragma unroll
        for (int c = 0; c < CPL; c++) acc[c] += alpha * hr[c * 64 + lane];
    }
#pragma unroll
    for (int c = 0; c < CPL; c++) {
        float v = acc[c] + bias[c * 64 + lane];
        v = (v > 0.f) ? v : expm1f(v);  // jax.nn.elu
        xout[(size_t)node * DOUT + c * 64 + lane] = v;
    }
}

// ---------------- pool (mean over batch segment) + concat + final linear ----------------

__global__ __launch_bounds__(64) void pool_final_kernel(
    const float* __restrict__ x /* N x 64 */, const int* __restrict__ batch,
    const float* __restrict__ xnorm /* G x 16 */, const float* __restrict__ linW /* 80 x 64 */,
    const float* __restrict__ linb, float* __restrict__ out /* G x 64 */, int n) {
    int g = blockIdx.x, t = threadIdx.x;
    int lo = lowerBound(batch, n, g);
    int hi = lowerBound(batch, n, g + 1);
    float sum = 0.f;
    for (int i = lo; i < hi; i++) sum += x[(size_t)i * 64 + t];
    float cnt = (float)(hi - lo);
    float mean = sum / fmaxf(cnt, 1.f);
    __shared__ float gv[80];
    gv[t] = mean;
    if (t < 16) gv[64 + t] = xnorm[g * 16 + t];
    __syncthreads();
    float acc = linb[t];
#pragma unroll
    for (int k = 0; k < 80; k++) acc += gv[k] * linW[k * 64 + t];
    out[(size_t)g * 64 + t] = acc;
}

// ---------------- launch ----------------

extern "C" void kernel_launch(void* const* d_in, const int* in_sizes, int n_in,
                              void* d_out, int out_size, void* d_ws, size_t ws_size,
                              hipStream_t stream) {
    const float* x1  = (const float*)d_in[0];
    const float* x2  = (const float*)d_in[1];
    const int*   ei1 = (const int*)d_in[2];
    const int*   ei2 = (const int*)d_in[3];
    const int*   batch = (const int*)d_in[4];
    // d_in[5] = half_y (unused by reference)
    const float* xn1 = (const float*)d_in[6];
    const float* xn2 = (const float*)d_in[7];
    const float* W1 = (const float*)d_in[8];
    const float* as1 = (const float*)d_in[9];
    const float* ad1 = (const float*)d_in[10];
    const float* b1 = (const float*)d_in[11];
    const float* W2 = (const float*)d_in[12];
    const float* as2 = (const float*)d_in[13];
    const float* ad2 = (const float*)d_in[14];
    const float* b2 = (const float*)d_in[15];
    const float* W3 = (const float*)d_in[16];
    const float* as3 = (const float*)d_in[17];
    const float* ad3 = (const float*)d_in[18];
    const float* b3 = (const float*)d_in[19];
    const float* linW = (const float*)d_in[20];
    const float* linb = (const float*)d_in[21];
    float* out = (float*)d_out;

    char* ws = (char*)d_ws;
    size_t off = 0;
    auto alloc = [&](size_t bytes) -> void* {
        void* p = ws + off;
        off += (bytes + 255) & ~(size_t)255;
        return p;
    };
    int* rowptr = (int*)alloc((N_NODES_C + 1) * sizeof(int));
    int* cursor = (int*)alloc(N_NODES_C * sizeof(int));
    int* csr    = (int*)alloc((size_t)(N_EDGES_C + N_NODES_C) * sizeof(int));
    float* als  = (float*)alloc(N_NODES_C * sizeof(float));
    float* ald  = (float*)alloc(N_NODES_C * sizeof(float));
    float* bufA = (float*)alloc((size_t)N_NODES_C * 128 * sizeof(float));
    float* bufB = (float*)alloc((size_t)N_NODES_C * 128 * sizeof(float));
    (void)ws_size; (void)in_sizes; (void)n_in; (void)out_size;

    const int AGG_GRID = (N_NODES_C + 3) / 4;

    for (int br = 0; br < 2; br++) {
        const float* x  = (br == 0) ? x1 : x2;
        const int*   ei = (br == 0) ? ei1 : ei2;
        const float* xn = (br == 0) ? xn1 : xn2;
        float* o = out + (size_t)br * N_GRAPHS_C * 64;

        // CSR build (dst-sorted adjacency incl. self loops)
        init_deg_kernel<<<(N_NODES_C + 255) / 256, 256, 0, stream>>>(cursor, N_NODES_C);
        count_kernel<<<2048, 256, 0, stream>>>(ei, cursor, N_EDGES_C);
        scan_kernel<<<1, 1024, 0, stream>>>(cursor, rowptr, N_NODES_C);
        scatter_kernel<<<2048, 256, 0, stream>>>(ei, cursor, csr, N_EDGES_C, N_NODES_C);

        // Layer 1: 7 -> 128
        linear_att_kernel<7, 128><<<2048, 128, 0, stream>>>(x, W1, as1, ad1, bufA, als, ald, N_NODES_C);
        gat_agg_kernel<128><<<AGG_GRID, 256, 0, stream>>>(rowptr, csr, als, ald, bufA, b1, bufB, N_NODES_C);
        // Layer 2: 128 -> 128
        linear_att_kernel<128, 128><<<2048, 128, 0, stream>>>(bufB, W2, as2, ad2, bufA, als, ald, N_NODES_C);
        gat_agg_kernel<128><<<AGG_GRID, 256, 0, stream>>>(rowptr, csr, als, ald, bufA, b2, bufB, N_NODES_C);
        // Layer 3: 128 -> 64
        linear_att_kernel<128, 64><<<2048, 64, 0, stream>>>(bufB, W3, as3, ad3, bufA, als, ald, N_NODES_C);
        gat_agg_kernel<64><<<AGG_GRID, 256, 0, stream>>>(rowptr, csr, als, ald, bufA, b3, bufB, N_NODES_C);

        // mean pool + concat + linear head
        pool_final_kernel<<<N_GRAPHS_C, 64, 0, stream>>>(bufB, batch, xn, linW, linb, o, N_NODES_C);
    }
}

// Round 3
// 1518.033 us; speedup vs baseline: 1.2759x; 1.2759x over previous
//
#include <hip/hip_runtime.h>
#include <math.h>

#define N_NODES_C 50000
#define N_EDGES_C 1600000
#define N_GRAPHS_C 2048

static __device__ __forceinline__ int lowerBound(const int* __restrict__ a, int n, int v) {
    int lo = 0, hi = n;
    while (lo < hi) {
        int mid = (lo + hi) >> 1;
        if (a[mid] < v) lo = mid + 1; else hi = mid;
    }
    return lo;
}

// ---------------- CSR build ----------------

__global__ void init_deg_kernel(int* __restrict__ deg, int n) {
    int i = blockIdx.x * blockDim.x + threadIdx.x;
    if (i < n) deg[i] = 1;  // self-loop contributes 1
}

__global__ void count_kernel(const int* __restrict__ ei, int* __restrict__ deg, int E) {
    for (int e = blockIdx.x * blockDim.x + threadIdx.x; e < E; e += gridDim.x * blockDim.x)
        atomicAdd(&deg[ei[E + e]], 1);  // dst row of edge_index
}

__global__ __launch_bounds__(1024) void scan_kernel(int* __restrict__ deg_cursor,
                                                    int* __restrict__ rowptr, int n) {
    __shared__ int part[1024];
    int t = threadIdx.x;
    int chunk = (n + 1023) >> 10;
    int beg = t * chunk;
    int end = min(beg + chunk, n);
    int s = 0;
    for (int i = beg; i < end; i++) s += deg_cursor[i];
    part[t] = s;
    __syncthreads();
    for (int off = 1; off < 1024; off <<= 1) {
        int v = (t >= off) ? part[t - off] : 0;
        __syncthreads();
        part[t] += v;
        __syncthreads();
    }
    if (t == 0) rowptr[n] = part[1023];
    int run = (t == 0) ? 0 : part[t - 1];
    for (int i = beg; i < end; i++) {
        int d = deg_cursor[i];
        rowptr[i] = run;
        deg_cursor[i] = run;  // becomes scatter cursor (in-place)
        run += d;
    }
}

__global__ void scatter_kernel(const int* __restrict__ ei, int* __restrict__ cursor,
                               int* __restrict__ csr, int E, int n) {
    int total = E + n;
    for (int idx = blockIdx.x * blockDim.x + threadIdx.x; idx < total; idx += gridDim.x * blockDim.x) {
        int s_, d_;
        if (idx < E) { s_ = ei[idx]; d_ = ei[E + idx]; }
        else         { s_ = d_ = idx - E; }  // self loop
        int pos = atomicAdd(&cursor[d_], 1);
        csr[pos] = s_;
    }
}

// ---------------- tiled GEMM + fused attention dots (DIN=128, DOUT in {128,64}) ----------------
// 64 nodes per block, 256 threads: thread (tx,ty) computes 4 nodes x (DOUT/16) outs.
// K chunked by 32, double-buffered LDS, float4 loads throughout.

template<int DIN, int DOUT>
__global__ __launch_bounds__(256) void linear_att_gemm(
    const float* __restrict__ x, const float* __restrict__ W,
    const float* __restrict__ avs, const float* __restrict__ avd,
    float* __restrict__ h, float* __restrict__ als, float* __restrict__ ald, int n) {
    constexpr int KC = 32;
    constexpr int NC = DIN / KC;          // 4 chunks for DIN=128
    constexpr int OPT = DOUT / 16;        // outs per thread: 8 or 4
    constexpr int WF4 = KC * DOUT / 4 / 256;  // W float4s per thread per chunk
    __shared__ float xs[2][64][KC + 4];
    __shared__ float Ws[2][KC][DOUT];

    const int tid = threadIdx.x;
    const int tx = tid & 15, ty = tid >> 4;
    const int nodeBase = blockIdx.x * 64;
    const int n0 = nodeBase + ty * 4;
    const int ob = tx * OPT;

    float a_s[OPT], a_d[OPT];
#pragma unroll
    for (int o = 0; o < OPT; o++) { a_s[o] = avs[ob + o]; a_d[o] = avd[ob + o]; }

    float acc[4][OPT];
#pragma unroll
    for (int i = 0; i < 4; i++)
#pragma unroll
        for (int o = 0; o < OPT; o++) acc[i][o] = 0.f;

    float4 xr[2], wr[WF4];

    auto stage_load = [&](int c) {
        int kb = c * KC;
#pragma unroll
        for (int q = 0; q < 2; q++) {
            int idx = tid + q * 256;
            int nd = idx >> 3, kq = idx & 7;
            int g = min(nodeBase + nd, n - 1);
            xr[q] = *(const float4*)&x[(size_t)g * DIN + kb + kq * 4];
        }
#pragma unroll
        for (int q = 0; q < WF4; q++) {
            int idx = tid + q * 256;
            int row = idx / (DOUT / 4), c4 = idx % (DOUT / 4);
            wr[q] = *(const float4*)&W[(size_t)(kb + row) * DOUT + c4 * 4];
        }
    };
    auto stage_write = [&](int b) {
#pragma unroll
        for (int q = 0; q < 2; q++) {
            int idx = tid + q * 256;
            int nd = idx >> 3, kq = idx & 7;
            *(float4*)&xs[b][nd][kq * 4] = xr[q];
        }
#pragma unroll
        for (int q = 0; q < WF4; q++) {
            int idx = tid + q * 256;
            int row = idx / (DOUT / 4), c4 = idx % (DOUT / 4);
            *(float4*)&Ws[b][row][c4 * 4] = wr[q];
        }
    };
    auto compute = [&](int b) {
#pragma unroll
        for (int k4 = 0; k4 < KC; k4 += 4) {
            float4 xv[4];
#pragma unroll
            for (int i = 0; i < 4; i++)
                xv[i] = *(const float4*)&xs[b][ty * 4 + i][k4];
#pragma unroll
            for (int kk = 0; kk < 4; kk++) {
                float wv[OPT];
#pragma unroll
                for (int o4 = 0; o4 < OPT; o4 += 4) {
                    float4 w4 = *(const float4*)&Ws[b][k4 + kk][ob + o4];
                    wv[o4] = w4.x; wv[o4 + 1] = w4.y; wv[o4 + 2] = w4.z; wv[o4 + 3] = w4.w;
                }
#pragma unroll
                for (int i = 0; i < 4; i++) {
                    float xk = (kk == 0) ? xv[i].x : (kk == 1) ? xv[i].y : (kk == 2) ? xv[i].z : xv[i].w;
#pragma unroll
                    for (int o = 0; o < OPT; o++) acc[i][o] += xk * wv[o];
                }
            }
        }
    };

    stage_load(0);
    stage_write(0);
    __syncthreads();
    int buf = 0;
    for (int c = 1; c < NC; c++) {
        stage_load(c);     // issue next chunk's global loads
        compute(buf);      // overlap their latency with current chunk's math
        stage_write(buf ^ 1);
        __syncthreads();
        buf ^= 1;
    }
    compute(buf);

#pragma unroll
    for (int i = 0; i < 4; i++) {
        int g = n0 + i;
        if (g < n) {
#pragma unroll
            for (int o4 = 0; o4 < OPT; o4 += 4) {
                float4 v;
                v.x = acc[i][o4]; v.y = acc[i][o4 + 1]; v.z = acc[i][o4 + 2]; v.w = acc[i][o4 + 3];
                *(float4*)&h[(size_t)g * DOUT + ob + o4] = v;
            }
            float ps = 0.f, pd = 0.f;
#pragma unroll
            for (int o = 0; o < OPT; o++) { ps += acc[i][o] * a_s[o]; pd += acc[i][o] * a_d[o]; }
#pragma unroll
            for (int off = 1; off < 16; off <<= 1) { ps += __shfl_xor(ps, off); pd += __shfl_xor(pd, off); }
            if (tx == 0) { als[g] = ps; ald[g] = pd; }
        }
    }
}

// ---------------- layer 1: DIN=7 -> DOUT=128 (memory-bound; no K tiling needed) ----------------

__global__ __launch_bounds__(256) void linear_att_l1(
    const float* __restrict__ x, const float* __restrict__ W,  // W [7][128]
    const float* __restrict__ avs, const float* __restrict__ avd,
    float* __restrict__ h, float* __restrict__ als, float* __restrict__ ald, int n) {
    __shared__ float Wl[7 * 128];
    __shared__ float xsh[32][8];
    int tid = threadIdx.x;
    for (int i = tid; i < 7 * 128; i += 256) Wl[i] = W[i];
    int nodeBase = blockIdx.x * 32;
    if (tid < 224) {
        int nd = tid / 7, k = tid % 7;
        int g = min(nodeBase + nd, n - 1);
        xsh[nd][k] = x[(size_t)g * 7 + k];
    }
    __syncthreads();
    int nl = tid >> 3;
    int og = (tid & 7) * 16;
    int g = nodeBase + nl;
    float acc[16];
#pragma unroll
    for (int o = 0; o < 16; o++) acc[o] = 0.f;
#pragma unroll
    for (int k = 0; k < 7; k++) {
        float xv = xsh[nl][k];
#pragma unroll
        for (int o = 0; o < 16; o++) acc[o] += xv * Wl[k * 128 + og + o];
    }
    if (g < n) {
#pragma unroll
        for (int o4 = 0; o4 < 16; o4 += 4) {
            float4 v; v.x = acc[o4]; v.y = acc[o4 + 1]; v.z = acc[o4 + 2]; v.w = acc[o4 + 3];
            *(float4*)&h[(size_t)g * 128 + og + o4] = v;
        }
        float ps = 0.f, pd = 0.f;
#pragma unroll
        for (int o = 0; o < 16; o++) { ps += acc[o] * avs[og + o]; pd += acc[o] * avd[og + o]; }
#pragma unroll
        for (int off = 1; off < 8; off <<= 1) { ps += __shfl_xor(ps, off); pd += __shfl_xor(pd, off); }
        if ((tid & 7) == 0) { als[g] = ps; ald[g] = pd; }
    }
}

// ---------------- softmax-weighted aggregation ----------------
// DOUT=128: 2 waves share one node (64 cols each), stats shared via LDS.
// DOUT=64:  1 wave per node. Pass B unrolled x4 for load ILP; alpha precomputed.

template<int DOUT>
__global__ __launch_bounds__(256) void gat_agg2(
    const int* __restrict__ rowptr, const int* __restrict__ csr,
    const float* __restrict__ als, const float* __restrict__ ald,
    const float* __restrict__ h, const float* __restrict__ bias,
    float* __restrict__ xout, int n) {
    constexpr int WPN = DOUT / 64;     // waves per node
    constexpr int NPB = 4 / WPN;       // nodes per block
    __shared__ int   s_src[NPB][64];
    __shared__ float s_alpha[NPB][64];
    __shared__ float s_ms[NPB][2];
    int tid = threadIdx.x;
    int w = tid >> 6, lane = tid & 63;
    int slot = w / WPN, half = w % WPN;
    int node = min(blockIdx.x * NPB + slot, n - 1);  // grids are exact; clamp is benign

    int beg = rowptr[node], end = rowptr[node + 1];
    int deg = end - beg;
    int lim = min(deg, 64);

    if (half == 0) {
        float adi = ald[node];
        float m = -INFINITY, s = 0.f;
        int src0 = 0; float e0 = -INFINITY;
        for (int idx = beg + lane; idx < end; idx += 64) {
            int src = csr[idx];
            float e = als[src] + adi;
            e = (e > 0.f) ? e : 0.2f * e;  // leaky_relu 0.2
            if (idx == beg + lane) { src0 = src; e0 = e; }
            if (e > m) { s *= expf(m - e); m = e; }
            s += expf(e - m);
        }
#pragma unroll
        for (int o = 1; o < 64; o <<= 1) {
            float m2 = __shfl_xor(m, o);
            float s2 = __shfl_xor(s, o);
            float M = fmaxf(m, m2);
            float t1 = (m == M) ? s : s * expf(m - M);
            float t2 = (m2 == M) ? s2 : s2 * expf(m2 - M);
            m = M; s = t1 + t2;
        }
        float inv_den = 1.f / s;
        s_src[slot][lane] = src0;
        s_alpha[slot][lane] = (lane < lim) ? expf(e0 - m) * inv_den : 0.f;
        if (lane == 0) { s_ms[slot][0] = m; s_ms[slot][1] = inv_den; }
    }
    __syncthreads();

    int col = half * 64 + lane;
    float acc = 0.f;
    int j = 0;
    for (; j + 4 <= lim; j += 4) {
        int is0 = s_src[slot][j], is1 = s_src[slot][j + 1], is2 = s_src[slot][j + 2], is3 = s_src[slot][j + 3];
        float a0 = s_alpha[slot][j], a1 = s_alpha[slot][j + 1], a2 = s_alpha[slot][j + 2], a3 = s_alpha[slot][j + 3];
        float v0 = h[(size_t)is0 * DOUT + col];
        float v1 = h[(size_t)is1 * DOUT + col];
        float v2 = h[(size_t)is2 * DOUT + col];
        float v3 = h[(size_t)is3 * DOUT + col];
        acc += a0 * v0 + a1 * v1 + a2 * v2 + a3 * v3;
    }
    for (; j < lim; j++) {
        acc += s_alpha[slot][j] * h[(size_t)s_src[slot][j] * DOUT + col];
    }
    if (deg > 64) {  // rare tail
        float m = s_ms[slot][0], inv_den = s_ms[slot][1];
        float adi = ald[node];
        for (int idx = beg + 64; idx < end; idx++) {
            int src = csr[idx];
            float e = als[src] + adi;
            e = (e > 0.f) ? e : 0.2f * e;
            acc += expf(e - m) * inv_den * h[(size_t)src * DOUT + col];
        }
    }
    float v = acc + bias[col];
    v = (v > 0.f) ? v : expm1f(v);  // jax.nn.elu
    xout[(size_t)node * DOUT + col] = v;
}

// ---------------- pool (mean over batch segment) + concat + final linear ----------------

__global__ __launch_bounds__(64) void pool_final_kernel(
    const float* __restrict__ x /* N x 64 */, const int* __restrict__ batch,
    const float* __restrict__ xnorm /* G x 16 */, const float* __restrict__ linW /* 80 x 64 */,
    const float* __restrict__ linb, float* __restrict__ out /* G x 64 */, int n) {
    int g = blockIdx.x, t = threadIdx.x;
    int lo = lowerBound(batch, n, g);
    int hi = lowerBound(batch, n, g + 1);
    float sum = 0.f;
    for (int i = lo; i < hi; i++) sum += x[(size_t)i * 64 + t];
    float cnt = (float)(hi - lo);
    float mean = sum / fmaxf(cnt, 1.f);
    __shared__ float gv[80];
    gv[t] = mean;
    if (t < 16) gv[64 + t] = xnorm[g * 16 + t];
    __syncthreads();
    float acc = linb[t];
#pragma unroll
    for (int k = 0; k < 80; k++) acc += gv[k] * linW[k * 64 + t];
    out[(size_t)g * 64 + t] = acc;
}

// ---------------- launch ----------------

extern "C" void kernel_launch(void* const* d_in, const int* in_sizes, int n_in,
                              void* d_out, int out_size, void* d_ws, size_t ws_size,
                              hipStream_t stream) {
    const float* x1  = (const float*)d_in[0];
    const float* x2  = (const float*)d_in[1];
    const int*   ei1 = (const int*)d_in[2];
    const int*   ei2 = (const int*)d_in[3];
    const int*   batch = (const int*)d_in[4];
    // d_in[5] = half_y (unused by reference)
    const float* xn1 = (const float*)d_in[6];
    const float* xn2 = (const float*)d_in[7];
    const float* W1 = (const float*)d_in[8];
    const float* as1 = (const float*)d_in[9];
    const float* ad1 = (const float*)d_in[10];
    const float* b1 = (const float*)d_in[11];
    const float* W2 = (const float*)d_in[12];
    const float* as2 = (const float*)d_in[13];
    const float* ad2 = (const float*)d_in[14];
    const float* b2 = (const float*)d_in[15];
    const float* W3 = (const float*)d_in[16];
    const float* as3 = (const float*)d_in[17];
    const float* ad3 = (const float*)d_in[18];
    const float* b3 = (const float*)d_in[19];
    const float* linW = (const float*)d_in[20];
    const float* linb = (const float*)d_in[21];
    float* out = (float*)d_out;

    char* ws = (char*)d_ws;
    size_t off = 0;
    auto alloc = [&](size_t bytes) -> void* {
        void* p = ws + off;
        off += (bytes + 255) & ~(size_t)255;
        return p;
    };
    int* rowptr = (int*)alloc((N_NODES_C + 1) * sizeof(int));
    int* cursor = (int*)alloc(N_NODES_C * sizeof(int));
    int* csr    = (int*)alloc((size_t)(N_EDGES_C + N_NODES_C) * sizeof(int));
    float* als  = (float*)alloc(N_NODES_C * sizeof(float));
    float* ald  = (float*)alloc(N_NODES_C * sizeof(float));
    float* bufA = (float*)alloc((size_t)N_NODES_C * 128 * sizeof(float));
    float* bufB = (float*)alloc((size_t)N_NODES_C * 128 * sizeof(float));
    (void)ws_size; (void)in_sizes; (void)n_in; (void)out_size;

    const int GEMM_GRID = (N_NODES_C + 63) / 64;

    for (int br = 0; br < 2; br++) {
        const float* x  = (br == 0) ? x1 : x2;
        const int*   ei = (br == 0) ? ei1 : ei2;
        const float* xn = (br == 0) ? xn1 : xn2;
        float* o = out + (size_t)br * N_GRAPHS_C * 64;

        // CSR build (dst-sorted adjacency incl. self loops)
        init_deg_kernel<<<(N_NODES_C + 255) / 256, 256, 0, stream>>>(cursor, N_NODES_C);
        count_kernel<<<2048, 256, 0, stream>>>(ei, cursor, N_EDGES_C);
        scan_kernel<<<1, 1024, 0, stream>>>(cursor, rowptr, N_NODES_C);
        scatter_kernel<<<2048, 256, 0, stream>>>(ei, cursor, csr, N_EDGES_C, N_NODES_C);

        // Layer 1: 7 -> 128
        linear_att_l1<<<(N_NODES_C + 31) / 32, 256, 0, stream>>>(x, W1, as1, ad1, bufA, als, ald, N_NODES_C);
        gat_agg2<128><<<N_NODES_C / 2, 256, 0, stream>>>(rowptr, csr, als, ald, bufA, b1, bufB, N_NODES_C);
        // Layer 2: 128 -> 128
        linear_att_gemm<128, 128><<<GEMM_GRID, 256, 0, stream>>>(bufB, W2, as2, ad2, bufA, als, ald, N_NODES_C);
        gat_agg2<128><<<N_NODES_C / 2, 256, 0, stream>>>(rowptr, csr, als, ald, bufA, b2, bufB, N_NODES_C);
        // Layer 3: 128 -> 64
        linear_att_gemm<128, 64><<<GEMM_GRID, 256, 0, stream>>>(bufB, W3, as3, ad3, bufA, als, ald, N_NODES_C);
        gat_agg2<64><<<N_NODES_C / 4, 256, 0, stream>>>(rowptr, csr, als, ald, bufA, b3, bufB, N_NODES_C);

        // mean pool + concat + linear head
        pool_final_kernel<<<N_GRAPHS_C, 64, 0, stream>>>(bufB, batch, xn, linW, linb, o, N_NODES_C);
    }
}

// Round 4
// 1031.188 us; speedup vs baseline: 1.8782x; 1.4721x over previous
//
#include <hip/hip_runtime.h>
#include <math.h>

#define N_NODES_C 50000
#define N_EDGES_C 1600000
#define N_GRAPHS_C 2048
#define NBUK 391  // ceil(50000 / 128) buckets of 128 dst nodes

static __device__ __forceinline__ int lowerBound(const int* __restrict__ a, int n, int v) {
    int lo = 0, hi = n;
    while (lo < hi) {
        int mid = (lo + hi) >> 1;
        if (a[mid] < v) lo = mid + 1; else hi = mid;
    }
    return lo;
}

// ---------------- CSR build v2: bucketed counting sort (dense writes only) ----------------

__global__ __launch_bounds__(256) void bucket_count_kernel(
    const int* __restrict__ ei, int* __restrict__ bucketCnt, int E) {
    __shared__ int lh[NBUK];
    int t = threadIdx.x;
    for (int i = t; i < NBUK; i += 256) lh[i] = 0;
    __syncthreads();
    for (int e = blockIdx.x * blockDim.x + t; e < E; e += gridDim.x * blockDim.x)
        atomicAdd(&lh[((unsigned)ei[E + e]) >> 7], 1);
    __syncthreads();
    for (int i = t; i < NBUK; i += 256) {
        int c = lh[i];
        if (c) atomicAdd(&bucketCnt[i], c);
    }
}

__global__ __launch_bounds__(512) void bucket_scan_kernel(
    const int* __restrict__ bucketCnt, int* __restrict__ bucketPtr, int* __restrict__ bucketCur) {
    __shared__ int v[512];
    int t = threadIdx.x;
    int x = (t < NBUK) ? bucketCnt[t] : 0;
    v[t] = x;
    __syncthreads();
    for (int off = 1; off < 512; off <<= 1) {
        int y = (t >= off) ? v[t - off] : 0;
        __syncthreads();
        v[t] += y;
        __syncthreads();
    }
    int excl = v[t] - x;
    if (t <= NBUK) bucketPtr[t] = excl;   // t == NBUK gets total (x=0 there)
    if (t < NBUK) bucketCur[t] = excl;
}

// Each block takes a contiguous edge slice; per-bucket LDS count -> one global
// reservation atomic per (block,bucket) -> dense packed writes into private ranges.
__global__ __launch_bounds__(256) void bucket_scatter_kernel(
    const int* __restrict__ ei, int* __restrict__ bucketCur,
    unsigned* __restrict__ bucketBuf, int E) {
    __shared__ int lh[NBUK];
    int t = threadIdx.x;
    for (int i = t; i < NBUK; i += 256) lh[i] = 0;
    __syncthreads();
    int per = (E + gridDim.x - 1) / gridDim.x;
    int beg = blockIdx.x * per;
    int end = min(beg + per, E);
    for (int e = beg + t; e < end; e += 256)
        atomicAdd(&lh[((unsigned)ei[E + e]) >> 7], 1);
    __syncthreads();
    for (int i = t; i < NBUK; i += 256) {
        int c = lh[i];
        lh[i] = c ? atomicAdd(&bucketCur[i], c) : 0;
    }
    __syncthreads();
    for (int e = beg + t; e < end; e += 256) {
        int s = ei[e], d = ei[E + e];
        int pos = atomicAdd(&lh[((unsigned)d) >> 7], 1);
        bucketBuf[pos] = (unsigned)s | ((unsigned)(d & 127) << 16);  // src < 65536
    }
}

// One block per bucket: fine histogram (+1 self loop), scan -> rowptr, self-loop
// first, then scatter src via LDS cursors into the bucket's contiguous csr window.
__global__ __launch_bounds__(256) void csr_finalize_kernel(
    const int* __restrict__ bucketPtr, const unsigned* __restrict__ bucketBuf,
    int* __restrict__ rowptr, int* __restrict__ csr, int n) {
    __shared__ int hist[128], sc[128], cur[128];
    int b = blockIdx.x, t = threadIdx.x;
    int base = b << 7;
    int nb = min(128, n - base);
    if (t < 128) hist[t] = (t < nb) ? 1 : 0;  // self loop
    __syncthreads();
    int ebeg = bucketPtr[b], eend = bucketPtr[b + 1];
    for (int i = ebeg + t; i < eend; i += 256)
        atomicAdd(&hist[bucketBuf[i] >> 16], 1);
    __syncthreads();
    if (t < 128) sc[t] = hist[t];
    __syncthreads();
    for (int off = 1; off < 128; off <<= 1) {
        int y = 0;
        if (t < 128 && t >= off) y = sc[t - off];
        __syncthreads();
        if (t < 128) sc[t] += y;
        __syncthreads();
    }
    int csrStart = ebeg + base;  // edges before bucket + self loops before bucket
    if (t < nb) {
        int rpos = csrStart + sc[t] - hist[t];
        rowptr[base + t] = rpos;
        csr[rpos] = base + t;    // self-loop entry first
        cur[t] = rpos + 1;
    }
    if (b == 0 && t == 0) rowptr[n] = bucketPtr[NBUK] + n;
    __syncthreads();
    for (int i = ebeg + t; i < eend; i += 256) {
        unsigned v = bucketBuf[i];
        int pos = atomicAdd(&cur[v >> 16], 1);
        csr[pos] = (int)(v & 0xFFFFu);
    }
}

// ---------------- tiled GEMM + fused attention dots (DIN=128, DOUT in {128,64}) ----------------

template<int DIN, int DOUT>
__global__ __launch_bounds__(256) void linear_att_gemm(
    const float* __restrict__ x, const float* __restrict__ W,
    const float* __restrict__ avs, const float* __restrict__ avd,
    float* __restrict__ h, float* __restrict__ als, float* __restrict__ ald, int n) {
    constexpr int KC = 32;
    constexpr int NC = DIN / KC;
    constexpr int OPT = DOUT / 16;
    constexpr int WF4 = KC * DOUT / 4 / 256;
    __shared__ float xs[2][64][KC + 4];
    __shared__ float Ws[2][KC][DOUT];

    const int tid = threadIdx.x;
    const int tx = tid & 15, ty = tid >> 4;
    const int nodeBase = blockIdx.x * 64;
    const int n0 = nodeBase + ty * 4;
    const int ob = tx * OPT;

    float a_s[OPT], a_d[OPT];
#pragma unroll
    for (int o = 0; o < OPT; o++) { a_s[o] = avs[ob + o]; a_d[o] = avd[ob + o]; }

    float acc[4][OPT];
#pragma unroll
    for (int i = 0; i < 4; i++)
#pragma unroll
        for (int o = 0; o < OPT; o++) acc[i][o] = 0.f;

    float4 xr[2], wr[WF4];

    auto stage_load = [&](int c) {
        int kb = c * KC;
#pragma unroll
        for (int q = 0; q < 2; q++) {
            int idx = tid + q * 256;
            int nd = idx >> 3, kq = idx & 7;
            int g = min(nodeBase + nd, n - 1);
            xr[q] = *(const float4*)&x[(size_t)g * DIN + kb + kq * 4];
        }
#pragma unroll
        for (int q = 0; q < WF4; q++) {
            int idx = tid + q * 256;
            int row = idx / (DOUT / 4), c4 = idx % (DOUT / 4);
            wr[q] = *(const float4*)&W[(size_t)(kb + row) * DOUT + c4 * 4];
        }
    };
    auto stage_write = [&](int b) {
#pragma unroll
        for (int q = 0; q < 2; q++) {
            int idx = tid + q * 256;
            int nd = idx >> 3, kq = idx & 7;
            *(float4*)&xs[b][nd][kq * 4] = xr[q];
        }
#pragma unroll
        for (int q = 0; q < WF4; q++) {
            int idx = tid + q * 256;
            int row = idx / (DOUT / 4), c4 = idx % (DOUT / 4);
            *(float4*)&Ws[b][row][c4 * 4] = wr[q];
        }
    };
    auto compute = [&](int b) {
#pragma unroll
        for (int k4 = 0; k4 < KC; k4 += 4) {
            float4 xv[4];
#pragma unroll
            for (int i = 0; i < 4; i++)
                xv[i] = *(const float4*)&xs[b][ty * 4 + i][k4];
#pragma unroll
            for (int kk = 0; kk < 4; kk++) {
                float wv[OPT];
#pragma unroll
                for (int o4 = 0; o4 < OPT; o4 += 4) {
                    float4 w4 = *(const float4*)&Ws[b][k4 + kk][ob + o4];
                    wv[o4] = w4.x; wv[o4 + 1] = w4.y; wv[o4 + 2] = w4.z; wv[o4 + 3] = w4.w;
                }
#pragma unroll
                for (int i = 0; i < 4; i++) {
                    float xk = (kk == 0) ? xv[i].x : (kk == 1) ? xv[i].y : (kk == 2) ? xv[i].z : xv[i].w;
#pragma unroll
                    for (int o = 0; o < OPT; o++) acc[i][o] += xk * wv[o];
                }
            }
        }
    };

    stage_load(0);
    stage_write(0);
    __syncthreads();
    int buf = 0;
    for (int c = 1; c < NC; c++) {
        stage_load(c);
        compute(buf);
        stage_write(buf ^ 1);
        __syncthreads();
        buf ^= 1;
    }
    compute(buf);

#pragma unroll
    for (int i = 0; i < 4; i++) {
        int g = n0 + i;
        if (g < n) {
#pragma unroll
            for (int o4 = 0; o4 < OPT; o4 += 4) {
                float4 v;
                v.x = acc[i][o4]; v.y = acc[i][o4 + 1]; v.z = acc[i][o4 + 2]; v.w = acc[i][o4 + 3];
                *(float4*)&h[(size_t)g * DOUT + ob + o4] = v;
            }
            float ps = 0.f, pd = 0.f;
#pragma unroll
            for (int o = 0; o < OPT; o++) { ps += acc[i][o] * a_s[o]; pd += acc[i][o] * a_d[o]; }
#pragma unroll
            for (int off = 1; off < 16; off <<= 1) { ps += __shfl_xor(ps, off); pd += __shfl_xor(pd, off); }
            if (tx == 0) { als[g] = ps; ald[g] = pd; }
        }
    }
}

// ---------------- layer 1: DIN=7 -> DOUT=128 ----------------

__global__ __launch_bounds__(256) void linear_att_l1(
    const float* __restrict__ x, const float* __restrict__ W,
    const float* __restrict__ avs, const float* __restrict__ avd,
    float* __restrict__ h, float* __restrict__ als, float* __restrict__ ald, int n) {
    __shared__ float Wl[7 * 128];
    __shared__ float xsh[32][8];
    int tid = threadIdx.x;
    for (int i = tid; i < 7 * 128; i += 256) Wl[i] = W[i];
    int nodeBase = blockIdx.x * 32;
    if (tid < 224) {
        int nd = tid / 7, k = tid % 7;
        int g = min(nodeBase + nd, n - 1);
        xsh[nd][k] = x[(size_t)g * 7 + k];
    }
    __syncthreads();
    int nl = tid >> 3;
    int og = (tid & 7) * 16;
    int g = nodeBase + nl;
    float acc[16];
#pragma unroll
    for (int o = 0; o < 16; o++) acc[o] = 0.f;
#pragma unroll
    for (int k = 0; k < 7; k++) {
        float xv = xsh[nl][k];
#pragma unroll
        for (int o = 0; o < 16; o++) acc[o] += xv * Wl[k * 128 + og + o];
    }
    if (g < n) {
#pragma unroll
        for (int o4 = 0; o4 < 16; o4 += 4) {
            float4 v; v.x = acc[o4]; v.y = acc[o4 + 1]; v.z = acc[o4 + 2]; v.w = acc[o4 + 3];
            *(float4*)&h[(size_t)g * 128 + og + o4] = v;
        }
        float ps = 0.f, pd = 0.f;
#pragma unroll
        for (int o = 0; o < 16; o++) { ps += acc[o] * avs[og + o]; pd += acc[o] * avd[og + o]; }
#pragma unroll
        for (int off = 1; off < 8; off <<= 1) { ps += __shfl_xor(ps, off); pd += __shfl_xor(pd, off); }
        if ((tid & 7) == 0) { als[g] = ps; ald[g] = pd; }
    }
}

// ---------------- softmax-weighted aggregation ----------------

template<int DOUT>
__global__ __launch_bounds__(256) void gat_agg2(
    const int* __restrict__ rowptr, const int* __restrict__ csr,
    const float* __restrict__ als, const float* __restrict__ ald,
    const float* __restrict__ h, const float* __restrict__ bias,
    float* __restrict__ xout, int n) {
    constexpr int WPN = DOUT / 64;
    constexpr int NPB = 4 / WPN;
    __shared__ int   s_src[NPB][64];
    __shared__ float s_alpha[NPB][64];
    __shared__ float s_ms[NPB][2];
    int tid = threadIdx.x;
    int w = tid >> 6, lane = tid & 63;
    int slot = w / WPN, half = w % WPN;
    int node = min(blockIdx.x * NPB + slot, n - 1);

    int beg = rowptr[node], end = rowptr[node + 1];
    int deg = end - beg;
    int lim = min(deg, 64);

    if (half == 0) {
        float adi = ald[node];
        float m = -INFINITY, s = 0.f;
        int src0 = 0; float e0 = -INFINITY;
        for (int idx = beg + lane; idx < end; idx += 64) {
            int src = csr[idx];
            float e = als[src] + adi;
            e = (e > 0.f) ? e : 0.2f * e;  // leaky_relu 0.2
            if (idx == beg + lane) { src0 = src; e0 = e; }
            if (e > m) { s *= expf(m - e); m = e; }
            s += expf(e - m);
        }
#pragma unroll
        for (int o = 1; o < 64; o <<= 1) {
            float m2 = __shfl_xor(m, o);
            float s2 = __shfl_xor(s, o);
            float M = fmaxf(m, m2);
            float t1 = (m == M) ? s : s * expf(m - M);
            float t2 = (m2 == M) ? s2 : s2 * expf(m2 - M);
            m = M; s = t1 + t2;
        }
        float inv_den = 1.f / s;
        s_src[slot][lane] = src0;
        s_alpha[slot][lane] = (lane < lim) ? expf(e0 - m) * inv_den : 0.f;
        if (lane == 0) { s_ms[slot][0] = m; s_ms[slot][1] = inv_den; }
    }
    __syncthreads();

    int col = half * 64 + lane;
    float acc = 0.f;
    int j = 0;
    for (; j + 4 <= lim; j += 4) {
        int is0 = s_src[slot][j], is1 = s_src[slot][j + 1], is2 = s_src[slot][j + 2], is3 = s_src[slot][j + 3];
        float a0 = s_alpha[slot][j], a1 = s_alpha[slot][j + 1], a2 = s_alpha[slot][j + 2], a3 = s_alpha[slot][j + 3];
        float v0 = h[(size_t)is0 * DOUT + col];
        float v1 = h[(size_t)is1 * DOUT + col];
        float v2 = h[(size_t)is2 * DOUT + col];
        float v3 = h[(size_t)is3 * DOUT + col];
        acc += a0 * v0 + a1 * v1 + a2 * v2 + a3 * v3;
    }
    for (; j < lim; j++) {
        acc += s_alpha[slot][j] * h[(size_t)s_src[slot][j] * DOUT + col];
    }
    if (deg > 64) {
        float m = s_ms[slot][0], inv_den = s_ms[slot][1];
        float adi = ald[node];
        for (int idx = beg + 64; idx < end; idx++) {
            int src = csr[idx];
            float e = als[src] + adi;
            e = (e > 0.f) ? e : 0.2f * e;
            acc += expf(e - m) * inv_den * h[(size_t)src * DOUT + col];
        }
    }
    float v = acc + bias[col];
    v = (v > 0.f) ? v : expm1f(v);  // jax.nn.elu
    xout[(size_t)node * DOUT + col] = v;
}

// ---------------- pool (mean over batch segment) + concat + final linear ----------------

__global__ __launch_bounds__(64) void pool_final_kernel(
    const float* __restrict__ x, const int* __restrict__ batch,
    const float* __restrict__ xnorm, const float* __restrict__ linW,
    const float* __restrict__ linb, float* __restrict__ out, int n) {
    int g = blockIdx.x, t = threadIdx.x;
    int lo = lowerBound(batch, n, g);
    int hi = lowerBound(batch, n, g + 1);
    float sum = 0.f;
    for (int i = lo; i < hi; i++) sum += x[(size_t)i * 64 + t];
    float cnt = (float)(hi - lo);
    float mean = sum / fmaxf(cnt, 1.f);
    __shared__ float gv[80];
    gv[t] = mean;
    if (t < 16) gv[64 + t] = xnorm[g * 16 + t];
    __syncthreads();
    float acc = linb[t];
#pragma unroll
    for (int k = 0; k < 80; k++) acc += gv[k] * linW[k * 64 + t];
    out[(size_t)g * 64 + t] = acc;
}

// ---------------- launch ----------------

extern "C" void kernel_launch(void* const* d_in, const int* in_sizes, int n_in,
                              void* d_out, int out_size, void* d_ws, size_t ws_size,
                              hipStream_t stream) {
    const float* x1  = (const float*)d_in[0];
    const float* x2  = (const float*)d_in[1];
    const int*   ei1 = (const int*)d_in[2];
    const int*   ei2 = (const int*)d_in[3];
    const int*   batch = (const int*)d_in[4];
    const float* xn1 = (const float*)d_in[6];
    const float* xn2 = (const float*)d_in[7];
    const float* W1 = (const float*)d_in[8];
    const float* as1 = (const float*)d_in[9];
    const float* ad1 = (const float*)d_in[10];
    const float* b1 = (const float*)d_in[11];
    const float* W2 = (const float*)d_in[12];
    const float* as2 = (const float*)d_in[13];
    const float* ad2 = (const float*)d_in[14];
    const float* b2 = (const float*)d_in[15];
    const float* W3 = (const float*)d_in[16];
    const float* as3 = (const float*)d_in[17];
    const float* ad3 = (const float*)d_in[18];
    const float* b3 = (const float*)d_in[19];
    const float* linW = (const float*)d_in[20];
    const float* linb = (const float*)d_in[21];
    float* out = (float*)d_out;

    char* ws = (char*)d_ws;
    size_t off = 0;
    auto alloc = [&](size_t bytes) -> void* {
        void* p = ws + off;
        off += (bytes + 255) & ~(size_t)255;
        return p;
    };
    int* rowptr    = (int*)alloc((N_NODES_C + 1) * sizeof(int));
    int* csr       = (int*)alloc((size_t)(N_EDGES_C + N_NODES_C) * sizeof(int));
    float* als     = (float*)alloc(N_NODES_C * sizeof(float));
    float* ald     = (float*)alloc(N_NODES_C * sizeof(float));
    int* bucketCnt = (int*)alloc(NBUK * sizeof(int));
    int* bucketPtr = (int*)alloc((NBUK + 1) * sizeof(int));
    int* bucketCur = (int*)alloc(NBUK * sizeof(int));
    float* bufA    = (float*)alloc((size_t)N_NODES_C * 128 * sizeof(float));
    float* bufB    = (float*)alloc((size_t)N_NODES_C * 128 * sizeof(float));
    unsigned* bucketBuf = (unsigned*)bufA;  // aliased: dead ranges don't overlap in time
    (void)ws_size; (void)in_sizes; (void)n_in; (void)out_size;

    const int GEMM_GRID = (N_NODES_C + 63) / 64;

    for (int br = 0; br < 2; br++) {
        const float* x  = (br == 0) ? x1 : x2;
        const int*   ei = (br == 0) ? ei1 : ei2;
        const float* xn = (br == 0) ? xn1 : xn2;
        float* o = out + (size_t)br * N_GRAPHS_C * 64;

        // CSR build v2 (dst-sorted adjacency incl. self loops, dense writes)
        hipMemsetAsync(bucketCnt, 0, NBUK * sizeof(int), stream);
        bucket_count_kernel<<<1024, 256, 0, stream>>>(ei, bucketCnt, N_EDGES_C);
        bucket_scan_kernel<<<1, 512, 0, stream>>>(bucketCnt, bucketPtr, bucketCur);
        bucket_scatter_kernel<<<256, 256, 0, stream>>>(ei, bucketCur, bucketBuf, N_EDGES_C);
        csr_finalize_kernel<<<NBUK, 256, 0, stream>>>(bucketPtr, bucketBuf, rowptr, csr, N_NODES_C);

        // Layer 1: 7 -> 128   (overwrites bufA only after csr_finalize consumed bucketBuf)
        linear_att_l1<<<(N_NODES_C + 31) / 32, 256, 0, stream>>>(x, W1, as1, ad1, bufA, als, ald, N_NODES_C);
        gat_agg2<128><<<N_NODES_C / 2, 256, 0, stream>>>(rowptr, csr, als, ald, bufA, b1, bufB, N_NODES_C);
        // Layer 2: 128 -> 128
        linear_att_gemm<128, 128><<<GEMM_GRID, 256, 0, stream>>>(bufB, W2, as2, ad2, bufA, als, ald, N_NODES_C);
        gat_agg2<128><<<N_NODES_C / 2, 256, 0, stream>>>(rowptr, csr, als, ald, bufA, b2, bufB, N_NODES_C);
        // Layer 3: 128 -> 64
        linear_att_gemm<128, 64><<<GEMM_GRID, 256, 0, stream>>>(bufB, W3, as3, ad3, bufA, als, ald, N_NODES_C);
        gat_agg2<64><<<N_NODES_C / 4, 256, 0, stream>>>(rowptr, csr, als, ald, bufA, b3, bufB, N_NODES_C);

        // mean pool + concat + linear head
        pool_final_kernel<<<N_GRAPHS_C, 64, 0, stream>>>(bufB, batch, xn, linW, linb, o, N_NODES_C);
    }
}

// Round 5
// 760.557 us; speedup vs baseline: 2.5466x; 1.3558x over previous
//
#include <hip/hip_runtime.h>
#include <math.h>

#define N_NODES_C 50000
#define N_EDGES_C 1600000
#define N_GRAPHS_C 2048
#define NBUK 391  // ceil(50000 / 128) buckets of 128 dst nodes

static __device__ __forceinline__ int lowerBound(const int* __restrict__ a, int n, int v) {
    int lo = 0, hi = n;
    while (lo < hi) {
        int mid = (lo + hi) >> 1;
        if (a[mid] < v) lo = mid + 1; else hi = mid;
    }
    return lo;
}

// bf16 helpers: round-to-nearest-even pack, and unpack of a 2x-bf16 word
static __device__ __forceinline__ unsigned short f2bf(float f) {
    unsigned u = __float_as_uint(f);
    return (unsigned short)((u + 0x7FFFu + ((u >> 16) & 1u)) >> 16);
}
static __device__ __forceinline__ float blo(unsigned v) { return __uint_as_float(v << 16); }
static __device__ __forceinline__ float bhi(unsigned v) { return __uint_as_float(v & 0xFFFF0000u); }

// ---------------- CSR build v2: bucketed counting sort (dense writes only) ----------------

__global__ __launch_bounds__(256) void bucket_count_kernel(
    const int* __restrict__ ei, int* __restrict__ bucketCnt, int E) {
    __shared__ int lh[NBUK];
    int t = threadIdx.x;
    for (int i = t; i < NBUK; i += 256) lh[i] = 0;
    __syncthreads();
    for (int e = blockIdx.x * blockDim.x + t; e < E; e += gridDim.x * blockDim.x)
        atomicAdd(&lh[((unsigned)ei[E + e]) >> 7], 1);
    __syncthreads();
    for (int i = t; i < NBUK; i += 256) {
        int c = lh[i];
        if (c) atomicAdd(&bucketCnt[i], c);
    }
}

__global__ __launch_bounds__(512) void bucket_scan_kernel(
    const int* __restrict__ bucketCnt, int* __restrict__ bucketPtr, int* __restrict__ bucketCur) {
    __shared__ int v[512];
    int t = threadIdx.x;
    int x = (t < NBUK) ? bucketCnt[t] : 0;
    v[t] = x;
    __syncthreads();
    for (int off = 1; off < 512; off <<= 1) {
        int y = (t >= off) ? v[t - off] : 0;
        __syncthreads();
        v[t] += y;
        __syncthreads();
    }
    int excl = v[t] - x;
    if (t <= NBUK) bucketPtr[t] = excl;
    if (t < NBUK) bucketCur[t] = excl;
}

__global__ __launch_bounds__(256) void bucket_scatter_kernel(
    const int* __restrict__ ei, int* __restrict__ bucketCur,
    unsigned* __restrict__ bucketBuf, int E) {
    __shared__ int lh[NBUK];
    int t = threadIdx.x;
    for (int i = t; i < NBUK; i += 256) lh[i] = 0;
    __syncthreads();
    int per = (E + gridDim.x - 1) / gridDim.x;
    int beg = blockIdx.x * per;
    int end = min(beg + per, E);
    for (int e = beg + t; e < end; e += 256)
        atomicAdd(&lh[((unsigned)ei[E + e]) >> 7], 1);
    __syncthreads();
    for (int i = t; i < NBUK; i += 256) {
        int c = lh[i];
        lh[i] = c ? atomicAdd(&bucketCur[i], c) : 0;
    }
    __syncthreads();
    for (int e = beg + t; e < end; e += 256) {
        int s = ei[e], d = ei[E + e];
        int pos = atomicAdd(&lh[((unsigned)d) >> 7], 1);
        bucketBuf[pos] = (unsigned)s | ((unsigned)(d & 127) << 16);
    }
}

__global__ __launch_bounds__(256) void csr_finalize_kernel(
    const int* __restrict__ bucketPtr, const unsigned* __restrict__ bucketBuf,
    int* __restrict__ rowptr, int* __restrict__ csr, int n) {
    __shared__ int hist[128], sc[128], cur[128];
    int b = blockIdx.x, t = threadIdx.x;
    int base = b << 7;
    int nb = min(128, n - base);
    if (t < 128) hist[t] = (t < nb) ? 1 : 0;
    __syncthreads();
    int ebeg = bucketPtr[b], eend = bucketPtr[b + 1];
    for (int i = ebeg + t; i < eend; i += 256)
        atomicAdd(&hist[bucketBuf[i] >> 16], 1);
    __syncthreads();
    if (t < 128) sc[t] = hist[t];
    __syncthreads();
    for (int off = 1; off < 128; off <<= 1) {
        int y = 0;
        if (t < 128 && t >= off) y = sc[t - off];
        __syncthreads();
        if (t < 128) sc[t] += y;
        __syncthreads();
    }
    int csrStart = ebeg + base;
    if (t < nb) {
        int rpos = csrStart + sc[t] - hist[t];
        rowptr[base + t] = rpos;
        csr[rpos] = base + t;
        cur[t] = rpos + 1;
    }
    if (b == 0 && t == 0) rowptr[n] = bucketPtr[NBUK] + n;
    __syncthreads();
    for (int i = ebeg + t; i < eend; i += 256) {
        unsigned v = bucketBuf[i];
        int pos = atomicAdd(&cur[v >> 16], 1);
        csr[pos] = (int)(v & 0xFFFFu);
    }
}

// ---------------- tiled GEMM + fused attention dots; h written packed bf16 ----------------

template<int DIN, int DOUT>
__global__ __launch_bounds__(256) void linear_att_gemm(
    const float* __restrict__ x, const float* __restrict__ W,
    const float* __restrict__ avs, const float* __restrict__ avd,
    unsigned* __restrict__ hb, float* __restrict__ als, float* __restrict__ ald, int n) {
    constexpr int KC = 32;
    constexpr int NC = DIN / KC;
    constexpr int OPT = DOUT / 16;
    constexpr int WF4 = KC * DOUT / 4 / 256;
    __shared__ float xs[2][64][KC + 4];
    __shared__ float Ws[2][KC][DOUT];

    const int tid = threadIdx.x;
    const int tx = tid & 15, ty = tid >> 4;
    const int nodeBase = blockIdx.x * 64;
    const int n0 = nodeBase + ty * 4;
    const int ob = tx * OPT;

    float a_s[OPT], a_d[OPT];
#pragma unroll
    for (int o = 0; o < OPT; o++) { a_s[o] = avs[ob + o]; a_d[o] = avd[ob + o]; }

    float acc[4][OPT];
#pragma unroll
    for (int i = 0; i < 4; i++)
#pragma unroll
        for (int o = 0; o < OPT; o++) acc[i][o] = 0.f;

    float4 xr[2], wr[WF4];

    auto stage_load = [&](int c) {
        int kb = c * KC;
#pragma unroll
        for (int q = 0; q < 2; q++) {
            int idx = tid + q * 256;
            int nd = idx >> 3, kq = idx & 7;
            int g = min(nodeBase + nd, n - 1);
            xr[q] = *(const float4*)&x[(size_t)g * DIN + kb + kq * 4];
        }
#pragma unroll
        for (int q = 0; q < WF4; q++) {
            int idx = tid + q * 256;
            int row = idx / (DOUT / 4), c4 = idx % (DOUT / 4);
            wr[q] = *(const float4*)&W[(size_t)(kb + row) * DOUT + c4 * 4];
        }
    };
    auto stage_write = [&](int b) {
#pragma unroll
        for (int q = 0; q < 2; q++) {
            int idx = tid + q * 256;
            int nd = idx >> 3, kq = idx & 7;
            *(float4*)&xs[b][nd][kq * 4] = xr[q];
        }
#pragma unroll
        for (int q = 0; q < WF4; q++) {
            int idx = tid + q * 256;
            int row = idx / (DOUT / 4), c4 = idx % (DOUT / 4);
            *(float4*)&Ws[b][row][c4 * 4] = wr[q];
        }
    };
    auto compute = [&](int b) {
#pragma unroll
        for (int k4 = 0; k4 < KC; k4 += 4) {
            float4 xv[4];
#pragma unroll
            for (int i = 0; i < 4; i++)
                xv[i] = *(const float4*)&xs[b][ty * 4 + i][k4];
#pragma unroll
            for (int kk = 0; kk < 4; kk++) {
                float wv[OPT];
#pragma unroll
                for (int o4 = 0; o4 < OPT; o4 += 4) {
                    float4 w4 = *(const float4*)&Ws[b][k4 + kk][ob + o4];
                    wv[o4] = w4.x; wv[o4 + 1] = w4.y; wv[o4 + 2] = w4.z; wv[o4 + 3] = w4.w;
                }
#pragma unroll
                for (int i = 0; i < 4; i++) {
                    float xk = (kk == 0) ? xv[i].x : (kk == 1) ? xv[i].y : (kk == 2) ? xv[i].z : xv[i].w;
#pragma unroll
                    for (int o = 0; o < OPT; o++) acc[i][o] += xk * wv[o];
                }
            }
        }
    };

    stage_load(0);
    stage_write(0);
    __syncthreads();
    int buf = 0;
    for (int c = 1; c < NC; c++) {
        stage_load(c);
        compute(buf);
        stage_write(buf ^ 1);
        __syncthreads();
        buf ^= 1;
    }
    compute(buf);

#pragma unroll
    for (int i = 0; i < 4; i++) {
        int g = n0 + i;
        if (g < n) {
            unsigned pk[OPT / 2];
#pragma unroll
            for (int o = 0; o < OPT; o += 2)
                pk[o >> 1] = (unsigned)f2bf(acc[i][o]) | ((unsigned)f2bf(acc[i][o + 1]) << 16);
            if constexpr (OPT == 8) {
                uint4 v; v.x = pk[0]; v.y = pk[1]; v.z = pk[2]; v.w = pk[3];
                *(uint4*)&hb[(size_t)g * (DOUT / 2) + (ob >> 1)] = v;
            } else {
                uint2 v; v.x = pk[0]; v.y = pk[1];
                *(uint2*)&hb[(size_t)g * (DOUT / 2) + (ob >> 1)] = v;
            }
            float ps = 0.f, pd = 0.f;
#pragma unroll
            for (int o = 0; o < OPT; o++) { ps += acc[i][o] * a_s[o]; pd += acc[i][o] * a_d[o]; }
#pragma unroll
            for (int off = 1; off < 16; off <<= 1) { ps += __shfl_xor(ps, off); pd += __shfl_xor(pd, off); }
            if (tx == 0) { als[g] = ps; ald[g] = pd; }
        }
    }
}

// ---------------- layer 1: DIN=7 -> DOUT=128, bf16 h out ----------------

__global__ __launch_bounds__(256) void linear_att_l1(
    const float* __restrict__ x, const float* __restrict__ W,
    const float* __restrict__ avs, const float* __restrict__ avd,
    unsigned* __restrict__ hb, float* __restrict__ als, float* __restrict__ ald, int n) {
    __shared__ float Wl[7 * 128];
    __shared__ float xsh[32][8];
    int tid = threadIdx.x;
    for (int i = tid; i < 7 * 128; i += 256) Wl[i] = W[i];
    int nodeBase = blockIdx.x * 32;
    if (tid < 224) {
        int nd = tid / 7, k = tid % 7;
        int g = min(nodeBase + nd, n - 1);
        xsh[nd][k] = x[(size_t)g * 7 + k];
    }
    __syncthreads();
    int nl = tid >> 3;
    int og = (tid & 7) * 16;
    int g = nodeBase + nl;
    float acc[16];
#pragma unroll
    for (int o = 0; o < 16; o++) acc[o] = 0.f;
#pragma unroll
    for (int k = 0; k < 7; k++) {
        float xv = xsh[nl][k];
#pragma unroll
        for (int o = 0; o < 16; o++) acc[o] += xv * Wl[k * 128 + og + o];
    }
    if (g < n) {
        unsigned pk[8];
#pragma unroll
        for (int o = 0; o < 16; o += 2)
            pk[o >> 1] = (unsigned)f2bf(acc[o]) | ((unsigned)f2bf(acc[o + 1]) << 16);
        uint4 v0, v1;
        v0.x = pk[0]; v0.y = pk[1]; v0.z = pk[2]; v0.w = pk[3];
        v1.x = pk[4]; v1.y = pk[5]; v1.z = pk[6]; v1.w = pk[7];
        *(uint4*)&hb[(size_t)g * 64 + (og >> 1)] = v0;
        *(uint4*)&hb[(size_t)g * 64 + (og >> 1) + 4] = v1;
        float ps = 0.f, pd = 0.f;
#pragma unroll
        for (int o = 0; o < 16; o++) { ps += acc[o] * avs[og + o]; pd += acc[o] * avd[og + o]; }
#pragma unroll
        for (int off = 1; off < 8; off <<= 1) { ps += __shfl_xor(ps, off); pd += __shfl_xor(pd, off); }
        if ((tid & 7) == 0) { als[g] = ps; ald[g] = pd; }
    }
}

// ---------------- softmax-weighted aggregation over bf16 h, 1 wave per node ----------------
// DOUT=128: lane owns col pair {2*lane, 2*lane+1}; one 4B load per edge-row.
// DOUT=64:  two 32-lane halves process two edges concurrently; shfl_xor(32) combine.

template<int DOUT>
__global__ __launch_bounds__(256) void gat_agg3(
    const int* __restrict__ rowptr, const int* __restrict__ csr,
    const float* __restrict__ als, const float* __restrict__ ald,
    const unsigned* __restrict__ hb, const float* __restrict__ bias,
    float* __restrict__ xout, int n) {
    constexpr int RSU = DOUT / 2;  // h row stride in uints
    __shared__ int   s_src[4][64];
    __shared__ float s_alpha[4][64];
    __shared__ float s_ms[4][2];
    int tid = threadIdx.x;
    int w = tid >> 6, lane = tid & 63;
    int node = min(blockIdx.x * 4 + w, n - 1);
    int beg = rowptr[node], end = rowptr[node + 1];
    int deg = end - beg, lim = min(deg, 64);
    float adi = ald[node];

    // pass A: online softmax stats, lane-parallel
    float m = -INFINITY, s = 0.f;
    int src0 = 0; float e0 = -INFINITY;
    for (int idx = beg + lane; idx < end; idx += 64) {
        int src = csr[idx];
        float e = als[src] + adi;
        e = (e > 0.f) ? e : 0.2f * e;  // leaky_relu 0.2
        if (idx == beg + lane) { src0 = src; e0 = e; }
        if (e > m) { s *= expf(m - e); m = e; }
        s += expf(e - m);
    }
#pragma unroll
    for (int o = 1; o < 64; o <<= 1) {
        float m2 = __shfl_xor(m, o);
        float s2 = __shfl_xor(s, o);
        float M = fmaxf(m, m2);
        float t1 = (m == M) ? s : s * expf(m - M);
        float t2 = (m2 == M) ? s2 : s2 * expf(m2 - M);
        m = M; s = t1 + t2;
    }
    float inv_den = 1.f / s;
    s_src[w][lane] = src0;
    s_alpha[w][lane] = (lane < lim) ? expf(e0 - m) * inv_den : 0.f;
    if (lane == 0) { s_ms[w][0] = m; s_ms[w][1] = inv_den; }
    __syncthreads();

    float accx = 0.f, accy = 0.f;
    if constexpr (DOUT == 128) {
        int j = 0;
        for (; j + 4 <= lim; j += 4) {
            int i0 = s_src[w][j], i1 = s_src[w][j + 1], i2 = s_src[w][j + 2], i3 = s_src[w][j + 3];
            float a0 = s_alpha[w][j], a1 = s_alpha[w][j + 1], a2 = s_alpha[w][j + 2], a3 = s_alpha[w][j + 3];
            unsigned v0 = hb[(size_t)i0 * RSU + lane];
            unsigned v1 = hb[(size_t)i1 * RSU + lane];
            unsigned v2 = hb[(size_t)i2 * RSU + lane];
            unsigned v3 = hb[(size_t)i3 * RSU + lane];
            accx += a0 * blo(v0) + a1 * blo(v1) + a2 * blo(v2) + a3 * blo(v3);
            accy += a0 * bhi(v0) + a1 * bhi(v1) + a2 * bhi(v2) + a3 * bhi(v3);
        }
        for (; j < lim; j++) {
            unsigned v = hb[(size_t)s_src[w][j] * RSU + lane];
            float a = s_alpha[w][j];
            accx += a * blo(v); accy += a * bhi(v);
        }
        if (deg > 64) {
            float mm = s_ms[w][0], iv = s_ms[w][1];
            for (int idx = beg + 64; idx < end; idx++) {
                int src = csr[idx];
                float e = als[src] + adi;
                e = (e > 0.f) ? e : 0.2f * e;
                float a = expf(e - mm) * iv;
                unsigned v = hb[(size_t)src * RSU + lane];
                accx += a * blo(v); accy += a * bhi(v);
            }
        }
        int c0 = lane * 2;
        float vx = accx + bias[c0], vy = accy + bias[c0 + 1];
        vx = (vx > 0.f) ? vx : expm1f(vx);
        vy = (vy > 0.f) ? vy : expm1f(vy);
        *(float2*)&xout[(size_t)node * 128 + c0] = make_float2(vx, vy);
    } else {
        int half = lane >> 5, lcol = lane & 31;
        int limUp = (lim + 3) & ~3;  // s_alpha is 0-padded, s_src valid
        for (int j = 0; j < limUp; j += 4) {
            int je0 = j + half, je1 = j + 2 + half;
            int i0 = s_src[w][je0], i1 = s_src[w][je1];
            float a0 = s_alpha[w][je0], a1 = s_alpha[w][je1];
            unsigned v0 = hb[(size_t)i0 * RSU + lcol];
            unsigned v1 = hb[(size_t)i1 * RSU + lcol];
            accx += a0 * blo(v0) + a1 * blo(v1);
            accy += a0 * bhi(v0) + a1 * bhi(v1);
        }
        if (deg > 64) {
            float mm = s_ms[w][0], iv = s_ms[w][1];
            for (int idx = beg + 64; idx < end; idx++) {
                int src = csr[idx];
                float e = als[src] + adi;
                e = (e > 0.f) ? e : 0.2f * e;
                float a = expf(e - mm) * iv;
                if (half == 0) {
                    unsigned v = hb[(size_t)src * RSU + lcol];
                    accx += a * blo(v); accy += a * bhi(v);
                }
            }
        }
        accx += __shfl_xor(accx, 32);
        accy += __shfl_xor(accy, 32);
        if (half == 0) {
            int c0 = lcol * 2;
            float vx = accx + bias[c0], vy = accy + bias[c0 + 1];
            vx = (vx > 0.f) ? vx : expm1f(vx);
            vy = (vy > 0.f) ? vy : expm1f(vy);
            *(float2*)&xout[(size_t)node * 64 + c0] = make_float2(vx, vy);
        }
    }
}

// ---------------- pool (mean over batch segment) + concat + final linear ----------------

__global__ __launch_bounds__(64) void pool_final_kernel(
    const float* __restrict__ x, const int* __restrict__ batch,
    const float* __restrict__ xnorm, const float* __restrict__ linW,
    const float* __restrict__ linb, float* __restrict__ out, int n) {
    int g = blockIdx.x, t = threadIdx.x;
    int lo = lowerBound(batch, n, g);
    int hi = lowerBound(batch, n, g + 1);
    float sum = 0.f;
    for (int i = lo; i < hi; i++) sum += x[(size_t)i * 64 + t];
    float cnt = (float)(hi - lo);
    float mean = sum / fmaxf(cnt, 1.f);
    __shared__ float gv[80];
    gv[t] = mean;
    if (t < 16) gv[64 + t] = xnorm[g * 16 + t];
    __syncthreads();
    float acc = linb[t];
#pragma unroll
    for (int k = 0; k < 80; k++) acc += gv[k] * linW[k * 64 + t];
    out[(size_t)g * 64 + t] = acc;
}

// ---------------- launch ----------------

extern "C" void kernel_launch(void* const* d_in, const int* in_sizes, int n_in,
                              void* d_out, int out_size, void* d_ws, size_t ws_size,
                              hipStream_t stream) {
    const float* x1  = (const float*)d_in[0];
    const float* x2  = (const float*)d_in[1];
    const int*   ei1 = (const int*)d_in[2];
    const int*   ei2 = (const int*)d_in[3];
    const int*   batch = (const int*)d_in[4];
    const float* xn1 = (const float*)d_in[6];
    const float* xn2 = (const float*)d_in[7];
    const float* W1 = (const float*)d_in[8];
    const float* as1 = (const float*)d_in[9];
    const float* ad1 = (const float*)d_in[10];
    const float* b1 = (const float*)d_in[11];
    const float* W2 = (const float*)d_in[12];
    const float* as2 = (const float*)d_in[13];
    const float* ad2 = (const float*)d_in[14];
    const float* b2 = (const float*)d_in[15];
    const float* W3 = (const float*)d_in[16];
    const float* as3 = (const float*)d_in[17];
    const float* ad3 = (const float*)d_in[18];
    const float* b3 = (const float*)d_in[19];
    const float* linW = (const float*)d_in[20];
    const float* linb = (const float*)d_in[21];
    float* out = (float*)d_out;

    char* ws = (char*)d_ws;
    size_t off = 0;
    auto alloc = [&](size_t bytes) -> void* {
        void* p = ws + off;
        off += (bytes + 255) & ~(size_t)255;
        return p;
    };
    int* rowptr    = (int*)alloc((N_NODES_C + 1) * sizeof(int));
    int* csr       = (int*)alloc((size_t)(N_EDGES_C + N_NODES_C) * sizeof(int));
    float* als     = (float*)alloc(N_NODES_C * sizeof(float));
    float* ald     = (float*)alloc(N_NODES_C * sizeof(float));
    int* bucketCnt = (int*)alloc(NBUK * sizeof(int));
    int* bucketPtr = (int*)alloc((NBUK + 1) * sizeof(int));
    int* bucketCur = (int*)alloc(NBUK * sizeof(int));
    float* bufX    = (float*)alloc((size_t)N_NODES_C * 128 * sizeof(float));   // fp32 layer inputs
    unsigned* hb   = (unsigned*)alloc((size_t)N_NODES_C * 64 * sizeof(unsigned)); // bf16x2 h
    unsigned* bucketBuf = (unsigned*)bufX;  // aliased: lifetimes don't overlap
    (void)ws_size; (void)in_sizes; (void)n_in; (void)out_size;

    const int GEMM_GRID = (N_NODES_C + 63) / 64;
    const int AGG_GRID = (N_NODES_C + 3) / 4;

    for (int br = 0; br < 2; br++) {
        const float* x  = (br == 0) ? x1 : x2;
        const int*   ei = (br == 0) ? ei1 : ei2;
        const float* xn = (br == 0) ? xn1 : xn2;
        float* o = out + (size_t)br * N_GRAPHS_C * 64;

        // CSR build v2 (dst-sorted adjacency incl. self loops, dense writes)
        hipMemsetAsync(bucketCnt, 0, NBUK * sizeof(int), stream);
        bucket_count_kernel<<<1024, 256, 0, stream>>>(ei, bucketCnt, N_EDGES_C);
        bucket_scan_kernel<<<1, 512, 0, stream>>>(bucketCnt, bucketPtr, bucketCur);
        bucket_scatter_kernel<<<256, 256, 0, stream>>>(ei, bucketCur, bucketBuf, N_EDGES_C);
        csr_finalize_kernel<<<NBUK, 256, 0, stream>>>(bucketPtr, bucketBuf, rowptr, csr, N_NODES_C);

        // Layer 1: 7 -> 128
        linear_att_l1<<<(N_NODES_C + 31) / 32, 256, 0, stream>>>(x, W1, as1, ad1, hb, als, ald, N_NODES_C);
        gat_agg3<128><<<AGG_GRID, 256, 0, stream>>>(rowptr, csr, als, ald, hb, b1, bufX, N_NODES_C);
        // Layer 2: 128 -> 128
        linear_att_gemm<128, 128><<<GEMM_GRID, 256, 0, stream>>>(bufX, W2, as2, ad2, hb, als, ald, N_NODES_C);
        gat_agg3<128><<<AGG_GRID, 256, 0, stream>>>(rowptr, csr, als, ald, hb, b2, bufX, N_NODES_C);
        // Layer 3: 128 -> 64
        linear_att_gemm<128, 64><<<GEMM_GRID, 256, 0, stream>>>(bufX, W3, as3, ad3, hb, als, ald, N_NODES_C);
        gat_agg3<64><<<AGG_GRID, 256, 0, stream>>>(rowptr, csr, als, ald, hb, b3, bufX, N_NODES_C);

        // mean pool + concat + linear head
        pool_final_kernel<<<N_GRAPHS_C, 64, 0, stream>>>(bufX, batch, xn, linW, linb, o, N_NODES_C);
    }
}

// Round 6
// 618.623 us; speedup vs baseline: 3.1309x; 1.2294x over previous
//
#include <hip/hip_runtime.h>
#include <math.h>

#define N_NODES_C 50000
#define N_EDGES_C 1600000
#define N_GRAPHS_C 2048
#define NBUK 391  // ceil(50000 / 128) buckets of 128 dst nodes

typedef short short8 __attribute__((ext_vector_type(8)));
typedef float f32x4 __attribute__((ext_vector_type(4)));

static __device__ __forceinline__ int lowerBound(const int* __restrict__ a, int n, int v) {
    int lo = 0, hi = n;
    while (lo < hi) {
        int mid = (lo + hi) >> 1;
        if (a[mid] < v) lo = mid + 1; else hi = mid;
    }
    return lo;
}

// bf16 helpers: round-to-nearest-even pack, and unpack of a 2x-bf16 word
static __device__ __forceinline__ unsigned short f2bf(float f) {
    unsigned u = __float_as_uint(f);
    return (unsigned short)((u + 0x7FFFu + ((u >> 16) & 1u)) >> 16);
}
static __device__ __forceinline__ float blo(unsigned v) { return __uint_as_float(v << 16); }
static __device__ __forceinline__ float bhi(unsigned v) { return __uint_as_float(v & 0xFFFF0000u); }

// ---------------- CSR build v2: bucketed counting sort (dense writes only) ----------------

__global__ __launch_bounds__(256) void bucket_count_kernel(
    const int* __restrict__ ei, int* __restrict__ bucketCnt, int E) {
    __shared__ int lh[NBUK];
    int t = threadIdx.x;
    for (int i = t; i < NBUK; i += 256) lh[i] = 0;
    __syncthreads();
    for (int e = blockIdx.x * blockDim.x + t; e < E; e += gridDim.x * blockDim.x)
        atomicAdd(&lh[((unsigned)ei[E + e]) >> 7], 1);
    __syncthreads();
    for (int i = t; i < NBUK; i += 256) {
        int c = lh[i];
        if (c) atomicAdd(&bucketCnt[i], c);
    }
}

__global__ __launch_bounds__(512) void bucket_scan_kernel(
    const int* __restrict__ bucketCnt, int* __restrict__ bucketPtr, int* __restrict__ bucketCur) {
    __shared__ int v[512];
    int t = threadIdx.x;
    int x = (t < NBUK) ? bucketCnt[t] : 0;
    v[t] = x;
    __syncthreads();
    for (int off = 1; off < 512; off <<= 1) {
        int y = (t >= off) ? v[t - off] : 0;
        __syncthreads();
        v[t] += y;
        __syncthreads();
    }
    int excl = v[t] - x;
    if (t <= NBUK) bucketPtr[t] = excl;
    if (t < NBUK) bucketCur[t] = excl;
}

__global__ __launch_bounds__(256) void bucket_scatter_kernel(
    const int* __restrict__ ei, int* __restrict__ bucketCur,
    unsigned* __restrict__ bucketBuf, int E) {
    __shared__ int lh[NBUK];
    int t = threadIdx.x;
    for (int i = t; i < NBUK; i += 256) lh[i] = 0;
    __syncthreads();
    int per = (E + gridDim.x - 1) / gridDim.x;
    int beg = blockIdx.x * per;
    int end = min(beg + per, E);
    for (int e = beg + t; e < end; e += 256)
        atomicAdd(&lh[((unsigned)ei[E + e]) >> 7], 1);
    __syncthreads();
    for (int i = t; i < NBUK; i += 256) {
        int c = lh[i];
        lh[i] = c ? atomicAdd(&bucketCur[i], c) : 0;
    }
    __syncthreads();
    for (int e = beg + t; e < end; e += 256) {
        int s = ei[e], d = ei[E + e];
        int pos = atomicAdd(&lh[((unsigned)d) >> 7], 1);
        bucketBuf[pos] = (unsigned)s | ((unsigned)(d & 127) << 16);
    }
}

__global__ __launch_bounds__(256) void csr_finalize_kernel(
    const int* __restrict__ bucketPtr, const unsigned* __restrict__ bucketBuf,
    int* __restrict__ rowptr, int* __restrict__ csr, int n) {
    __shared__ int hist[128], sc[128], cur[128];
    int b = blockIdx.x, t = threadIdx.x;
    int base = b << 7;
    int nb = min(128, n - base);
    if (t < 128) hist[t] = (t < nb) ? 1 : 0;
    __syncthreads();
    int ebeg = bucketPtr[b], eend = bucketPtr[b + 1];
    for (int i = ebeg + t; i < eend; i += 256)
        atomicAdd(&hist[bucketBuf[i] >> 16], 1);
    __syncthreads();
    if (t < 128) sc[t] = hist[t];
    __syncthreads();
    for (int off = 1; off < 128; off <<= 1) {
        int y = 0;
        if (t < 128 && t >= off) y = sc[t - off];
        __syncthreads();
        if (t < 128) sc[t] += y;
        __syncthreads();
    }
    int csrStart = ebeg + base;
    if (t < nb) {
        int rpos = csrStart + sc[t] - hist[t];
        rowptr[base + t] = rpos;
        csr[rpos] = base + t;
        cur[t] = rpos + 1;
    }
    if (b == 0 && t == 0) rowptr[n] = bucketPtr[NBUK] + n;
    __syncthreads();
    for (int i = ebeg + t; i < eend; i += 256) {
        unsigned v = bucketBuf[i];
        int pos = atomicAdd(&cur[v >> 16], 1);
        csr[pos] = (int)(v & 0xFFFFu);
    }
}

// ---------------- weight convert + transpose: Wt[c][k] = bf16(W[k][c]) ----------------

__global__ __launch_bounds__(256) void wt_conv_kernel(
    const float* __restrict__ W, unsigned short* __restrict__ Wt, int K, int C) {
    int i = blockIdx.x * 256 + threadIdx.x;
    if (i < K * C) {
        int c = i / K, k = i - c * K;
        Wt[i] = f2bf(W[(size_t)k * C + c]);
    }
}

// ---------------- MFMA GEMM: h = x@W (bf16 in, fp32 acc), fused als/ald ----------------
// Block 256 = 4 waves; wave w handles 16 nodes. mfma(A=Wt frag, B=x frag):
// D col = lane&15 = node, D row = (lane>>4)*4+reg = 4 consecutive out-cols -> lane-local bf16 pack.

template<int DOUT>
__global__ __launch_bounds__(256) void gemm_mfma(
    const unsigned short* __restrict__ xb,   // [n][128] bf16
    const unsigned short* __restrict__ Wt,   // [DOUT][128] bf16 (transposed W)
    const float* __restrict__ avs, const float* __restrict__ avd,
    unsigned* __restrict__ hb,               // [n][DOUT/2] packed bf16x2
    float* __restrict__ als, float* __restrict__ ald, int n) {
    constexpr int NT = DOUT / 16;
    int w = threadIdx.x >> 6, l = threadIdx.x & 63;
    int lc = l & 15, lg = l >> 4;
    int n0 = blockIdx.x * 64 + w * 16;
    int nrow = min(n0 + lc, n - 1);
    f32x4 acc[NT];
#pragma unroll
    for (int ct = 0; ct < NT; ct++) acc[ct] = (f32x4){0.f, 0.f, 0.f, 0.f};
    const unsigned short* xrow = xb + (size_t)nrow * 128 + lg * 8;
#pragma unroll
    for (int kb = 0; kb < 128; kb += 32) {
        short8 xf = *(const short8*)(xrow + kb);
#pragma unroll
        for (int ct = 0; ct < NT; ct++) {
            short8 wf = *(const short8*)(Wt + (size_t)(ct * 16 + lc) * 128 + kb + lg * 8);
            acc[ct] = __builtin_amdgcn_mfma_f32_16x16x32_bf16(wf, xf, acc[ct], 0, 0, 0);
        }
    }
    int node = n0 + lc;
    bool ok = node < n;
    float ps = 0.f, pd = 0.f;
#pragma unroll
    for (int ct = 0; ct < NT; ct++) {
        int cb = ct * 16 + lg * 4;
#pragma unroll
        for (int j = 0; j < 4; j++) { ps += acc[ct][j] * avs[cb + j]; pd += acc[ct][j] * avd[cb + j]; }
        if (ok) {
            uint2 v;
            v.x = (unsigned)f2bf(acc[ct][0]) | ((unsigned)f2bf(acc[ct][1]) << 16);
            v.y = (unsigned)f2bf(acc[ct][2]) | ((unsigned)f2bf(acc[ct][3]) << 16);
            *(uint2*)&hb[(size_t)node * (DOUT / 2) + ct * 8 + lg * 2] = v;
        }
    }
    ps += __shfl_xor(ps, 16); ps += __shfl_xor(ps, 32);
    pd += __shfl_xor(pd, 16); pd += __shfl_xor(pd, 32);
    if (ok && lg == 0) { als[node] = ps; ald[node] = pd; }
}

// ---------------- layer 1: DIN=7 -> DOUT=128 (fp32 math, bf16 h out) ----------------

__global__ __launch_bounds__(256) void linear_att_l1(
    const float* __restrict__ x, const float* __restrict__ W,
    const float* __restrict__ avs, const float* __restrict__ avd,
    unsigned* __restrict__ hb, float* __restrict__ als, float* __restrict__ ald, int n) {
    __shared__ float Wl[7 * 128];
    __shared__ float xsh[32][8];
    int tid = threadIdx.x;
    for (int i = tid; i < 7 * 128; i += 256) Wl[i] = W[i];
    int nodeBase = blockIdx.x * 32;
    if (tid < 224) {
        int nd = tid / 7, k = tid % 7;
        int g = min(nodeBase + nd, n - 1);
        xsh[nd][k] = x[(size_t)g * 7 + k];
    }
    __syncthreads();
    int nl = tid >> 3;
    int og = (tid & 7) * 16;
    int g = nodeBase + nl;
    float acc[16];
#pragma unroll
    for (int o = 0; o < 16; o++) acc[o] = 0.f;
#pragma unroll
    for (int k = 0; k < 7; k++) {
        float xv = xsh[nl][k];
#pragma unroll
        for (int o = 0; o < 16; o++) acc[o] += xv * Wl[k * 128 + og + o];
    }
    if (g < n) {
        unsigned pk[8];
#pragma unroll
        for (int o = 0; o < 16; o += 2)
            pk[o >> 1] = (unsigned)f2bf(acc[o]) | ((unsigned)f2bf(acc[o + 1]) << 16);
        uint4 v0, v1;
        v0.x = pk[0]; v0.y = pk[1]; v0.z = pk[2]; v0.w = pk[3];
        v1.x = pk[4]; v1.y = pk[5]; v1.z = pk[6]; v1.w = pk[7];
        *(uint4*)&hb[(size_t)g * 64 + (og >> 1)] = v0;
        *(uint4*)&hb[(size_t)g * 64 + (og >> 1) + 4] = v1;
        float ps = 0.f, pd = 0.f;
#pragma unroll
        for (int o = 0; o < 16; o++) { ps += acc[o] * avs[og + o]; pd += acc[o] * avd[og + o]; }
#pragma unroll
        for (int off = 1; off < 8; off <<= 1) { ps += __shfl_xor(ps, off); pd += __shfl_xor(pd, off); }
        if ((tid & 7) == 0) { als[g] = ps; ald[g] = pd; }
    }
}

// ---------------- softmax-weighted aggregation over bf16 h, 1 wave per node ----------------
// OBF: write packed bf16 (feeds next MFMA GEMM); else fp32.

template<int DOUT, bool OBF>
__global__ __launch_bounds__(256) void gat_agg3(
    const int* __restrict__ rowptr, const int* __restrict__ csr,
    const float* __restrict__ als, const float* __restrict__ ald,
    const unsigned* __restrict__ hb, const float* __restrict__ bias,
    float* __restrict__ xout, int n) {
    constexpr int RSU = DOUT / 2;  // h row stride in uints
    __shared__ int   s_src[4][64];
    __shared__ float s_alpha[4][64];
    __shared__ float s_ms[4][2];
    int tid = threadIdx.x;
    int w = tid >> 6, lane = tid & 63;
    int node = min(blockIdx.x * 4 + w, n - 1);
    int beg = rowptr[node], end = rowptr[node + 1];
    int deg = end - beg, lim = min(deg, 64);
    float adi = ald[node];

    // pass A: online softmax stats, lane-parallel
    float m = -INFINITY, s = 0.f;
    int src0 = 0; float e0 = -INFINITY;
    for (int idx = beg + lane; idx < end; idx += 64) {
        int src = csr[idx];
        float e = als[src] + adi;
        e = (e > 0.f) ? e : 0.2f * e;  // leaky_relu 0.2
        if (idx == beg + lane) { src0 = src; e0 = e; }
        if (e > m) { s *= expf(m - e); m = e; }
        s += expf(e - m);
    }
#pragma unroll
    for (int o = 1; o < 64; o <<= 1) {
        float m2 = __shfl_xor(m, o);
        float s2 = __shfl_xor(s, o);
        float M = fmaxf(m, m2);
        float t1 = (m == M) ? s : s * expf(m - M);
        float t2 = (m2 == M) ? s2 : s2 * expf(m2 - M);
        m = M; s = t1 + t2;
    }
    float inv_den = 1.f / s;
    s_src[w][lane] = src0;
    s_alpha[w][lane] = (lane < lim) ? expf(e0 - m) * inv_den : 0.f;
    if (lane == 0) { s_ms[w][0] = m; s_ms[w][1] = inv_den; }
    __syncthreads();

    float accx = 0.f, accy = 0.f;
    if constexpr (DOUT == 128) {
        int j = 0;
        for (; j + 4 <= lim; j += 4) {
            int i0 = s_src[w][j], i1 = s_src[w][j + 1], i2 = s_src[w][j + 2], i3 = s_src[w][j + 3];
            float a0 = s_alpha[w][j], a1 = s_alpha[w][j + 1], a2 = s_alpha[w][j + 2], a3 = s_alpha[w][j + 3];
            unsigned v0 = hb[(size_t)i0 * RSU + lane];
            unsigned v1 = hb[(size_t)i1 * RSU + lane];
            unsigned v2 = hb[(size_t)i2 * RSU + lane];
            unsigned v3 = hb[(size_t)i3 * RSU + lane];
            accx += a0 * blo(v0) + a1 * blo(v1) + a2 * blo(v2) + a3 * blo(v3);
            accy += a0 * bhi(v0) + a1 * bhi(v1) + a2 * bhi(v2) + a3 * bhi(v3);
        }
        for (; j < lim; j++) {
            unsigned v = hb[(size_t)s_src[w][j] * RSU + lane];
            float a = s_alpha[w][j];
            accx += a * blo(v); accy += a * bhi(v);
        }
        if (deg > 64) {
            float mm = s_ms[w][0], iv = s_ms[w][1];
            for (int idx = beg + 64; idx < end; idx++) {
                int src = csr[idx];
                float e = als[src] + adi;
                e = (e > 0.f) ? e : 0.2f * e;
                float a = expf(e - mm) * iv;
                unsigned v = hb[(size_t)src * RSU + lane];
                accx += a * blo(v); accy += a * bhi(v);
            }
        }
        int c0 = lane * 2;
        float vx = accx + bias[c0], vy = accy + bias[c0 + 1];
        vx = (vx > 0.f) ? vx : expm1f(vx);
        vy = (vy > 0.f) ? vy : expm1f(vy);
        if constexpr (OBF) {
            ((unsigned*)xout)[(size_t)node * 64 + lane] =
                (unsigned)f2bf(vx) | ((unsigned)f2bf(vy) << 16);
        } else {
            *(float2*)&xout[(size_t)node * 128 + c0] = make_float2(vx, vy);
        }
    } else {
        int half = lane >> 5, lcol = lane & 31;
        int limUp = (lim + 3) & ~3;
        for (int j = 0; j < limUp; j += 4) {
            int je0 = j + half, je1 = j + 2 + half;
            int i0 = s_src[w][je0], i1 = s_src[w][je1];
            float a0 = s_alpha[w][je0], a1 = s_alpha[w][je1];
            unsigned v0 = hb[(size_t)i0 * RSU + lcol];
            unsigned v1 = hb[(size_t)i1 * RSU + lcol];
            accx += a0 * blo(v0) + a1 * blo(v1);
            accy += a0 * bhi(v0) + a1 * bhi(v1);
        }
        if (deg > 64) {
            float mm = s_ms[w][0], iv = s_ms[w][1];
            for (int idx = beg + 64; idx < end; idx++) {
                int src = csr[idx];
                float e = als[src] + adi;
                e = (e > 0.f) ? e : 0.2f * e;
                float a = expf(e - mm) * iv;
                if (half == 0) {
                    unsigned v = hb[(size_t)src * RSU + lcol];
                    accx += a * blo(v); accy += a * bhi(v);
                }
            }
        }
        accx += __shfl_xor(accx, 32);
        accy += __shfl_xor(accy, 32);
        if (half == 0) {
            int c0 = lcol * 2;
            float vx = accx + bias[c0], vy = accy + bias[c0 + 1];
            vx = (vx > 0.f) ? vx : expm1f(vx);
            vy = (vy > 0.f) ? vy : expm1f(vy);
            if constexpr (OBF) {
                ((unsigned*)xout)[(size_t)node * 32 + lcol] =
                    (unsigned)f2bf(vx) | ((unsigned)f2bf(vy) << 16);
            } else {
                *(float2*)&xout[(size_t)node * 64 + c0] = make_float2(vx, vy);
            }
        }
    }
}

// ---------------- pool (mean over batch segment) + concat + final linear ----------------

__global__ __launch_bounds__(64) void pool_final_kernel(
    const float* __restrict__ x, const int* __restrict__ batch,
    const float* __restrict__ xnorm, const float* __restrict__ linW,
    const float* __restrict__ linb, float* __restrict__ out, int n) {
    int g = blockIdx.x, t = threadIdx.x;
    int lo = lowerBound(batch, n, g);
    int hi = lowerBound(batch, n, g + 1);
    float sum = 0.f;
    for (int i = lo; i < hi; i++) sum += x[(size_t)i * 64 + t];
    float cnt = (float)(hi - lo);
    float mean = sum / fmaxf(cnt, 1.f);
    __shared__ float gv[80];
    gv[t] = mean;
    if (t < 16) gv[64 + t] = xnorm[g * 16 + t];
    __syncthreads();
    float acc = linb[t];
#pragma unroll
    for (int k = 0; k < 80; k++) acc += gv[k] * linW[k * 64 + t];
    out[(size_t)g * 64 + t] = acc;
}

// ---------------- launch ----------------

extern "C" void kernel_launch(void* const* d_in, const int* in_sizes, int n_in,
                              void* d_out, int out_size, void* d_ws, size_t ws_size,
                              hipStream_t stream) {
    const float* x1  = (const float*)d_in[0];
    const float* x2  = (const float*)d_in[1];
    const int*   ei1 = (const int*)d_in[2];
    const int*   ei2 = (const int*)d_in[3];
    const int*   batch = (const int*)d_in[4];
    const float* xn1 = (const float*)d_in[6];
    const float* xn2 = (const float*)d_in[7];
    const float* W1 = (const float*)d_in[8];
    const float* as1 = (const float*)d_in[9];
    const float* ad1 = (const float*)d_in[10];
    const float* b1 = (const float*)d_in[11];
    const float* W2 = (const float*)d_in[12];
    const float* as2 = (const float*)d_in[13];
    const float* ad2 = (const float*)d_in[14];
    const float* b2 = (const float*)d_in[15];
    const float* W3 = (const float*)d_in[16];
    const float* as3 = (const float*)d_in[17];
    const float* ad3 = (const float*)d_in[18];
    const float* b3 = (const float*)d_in[19];
    const float* linW = (const float*)d_in[20];
    const float* linb = (const float*)d_in[21];
    float* out = (float*)d_out;

    char* ws = (char*)d_ws;
    size_t off = 0;
    auto alloc = [&](size_t bytes) -> void* {
        void* p = ws + off;
        off += (bytes + 255) & ~(size_t)255;
        return p;
    };
    int* rowptr    = (int*)alloc((N_NODES_C + 1) * sizeof(int));
    int* csr       = (int*)alloc((size_t)(N_EDGES_C + N_NODES_C) * sizeof(int));
    float* als     = (float*)alloc(N_NODES_C * sizeof(float));
    float* ald     = (float*)alloc(N_NODES_C * sizeof(float));
    int* bucketCnt = (int*)alloc(NBUK * sizeof(int));
    int* bucketPtr = (int*)alloc((NBUK + 1) * sizeof(int));
    int* bucketCur = (int*)alloc(NBUK * sizeof(int));
    unsigned short* Wt2 = (unsigned short*)alloc(128 * 128 * sizeof(unsigned short));
    unsigned short* Wt3 = (unsigned short*)alloc(64 * 128 * sizeof(unsigned short));
    float* bufX    = (float*)alloc((size_t)N_NODES_C * 64 * sizeof(float));        // fp32 final agg out
    unsigned* hb   = (unsigned*)alloc((size_t)N_NODES_C * 64 * sizeof(unsigned));  // bf16x2 h
    unsigned short* xbb = (unsigned short*)alloc((size_t)N_NODES_C * 128 * sizeof(unsigned short)); // bf16 x
    unsigned* bucketBuf = (unsigned*)bufX;  // aliased: lifetimes don't overlap (pool consumes bufX before next CSR build)
    (void)ws_size; (void)in_sizes; (void)n_in; (void)out_size;

    const int GEMM_GRID = (N_NODES_C + 63) / 64;
    const int AGG_GRID = (N_NODES_C + 3) / 4;

    // one-time: W2/W3 -> bf16 transposed
    wt_conv_kernel<<<(128 * 128 + 255) / 256, 256, 0, stream>>>(W2, Wt2, 128, 128);
    wt_conv_kernel<<<(128 * 64 + 255) / 256, 256, 0, stream>>>(W3, Wt3, 128, 64);

    for (int br = 0; br < 2; br++) {
        const float* x  = (br == 0) ? x1 : x2;
        const int*   ei = (br == 0) ? ei1 : ei2;
        const float* xn = (br == 0) ? xn1 : xn2;
        float* o = out + (size_t)br * N_GRAPHS_C * 64;

        // CSR build (dst-sorted adjacency incl. self loops, dense writes)
        hipMemsetAsync(bucketCnt, 0, NBUK * sizeof(int), stream);
        bucket_count_kernel<<<1024, 256, 0, stream>>>(ei, bucketCnt, N_EDGES_C);
        bucket_scan_kernel<<<1, 512, 0, stream>>>(bucketCnt, bucketPtr, bucketCur);
        bucket_scatter_kernel<<<256, 256, 0, stream>>>(ei, bucketCur, bucketBuf, N_EDGES_C);
        csr_finalize_kernel<<<NBUK, 256, 0, stream>>>(bucketPtr, bucketBuf, rowptr, csr, N_NODES_C);

        // Layer 1: 7 -> 128
        linear_att_l1<<<(N_NODES_C + 31) / 32, 256, 0, stream>>>(x, W1, as1, ad1, hb, als, ald, N_NODES_C);
        gat_agg3<128, true><<<AGG_GRID, 256, 0, stream>>>(rowptr, csr, als, ald, hb, b1, (float*)xbb, N_NODES_C);
        // Layer 2: 128 -> 128 (MFMA)
        gemm_mfma<128><<<GEMM_GRID, 256, 0, stream>>>(xbb, Wt2, as2, ad2, hb, als, ald, N_NODES_C);
        gat_agg3<128, true><<<AGG_GRID, 256, 0, stream>>>(rowptr, csr, als, ald, hb, b2, (float*)xbb, N_NODES_C);
        // Layer 3: 128 -> 64 (MFMA)
        gemm_mfma<64><<<GEMM_GRID, 256, 0, stream>>>(xbb, Wt3, as3, ad3, hb, als, ald, N_NODES_C);
        gat_agg3<64, false><<<AGG_GRID, 256, 0, stream>>>(rowptr, csr, als, ald, hb, b3, bufX, N_NODES_C);

        // mean pool + concat + linear head
        pool_final_kernel<<<N_GRAPHS_C, 64, 0, stream>>>(bufX, batch, xn, linW, linb, o, N_NODES_C);
    }
}